// Round 1
// 496.403 us; speedup vs baseline: 1.0887x; 1.0887x over previous
//
#include <hip/hip_runtime.h>

#define DEV __device__ __forceinline__

typedef unsigned short bhalf;
typedef __attribute__((ext_vector_type(8))) short bf8v;
typedef __attribute__((ext_vector_type(4))) float f4;

namespace {
constexpr int TPB = 256;
constexpr float ATT_SCALE = 0.08838834764831845f; // 1/sqrt(128)

// ---- workspace byte offsets ----
constexpr size_t O_PT  = 0;          // bf16 [640][64][256]  modalities, zero-pad rows
constexpr size_t O_WTS = 20971520;   // bf16 transposed weights (see W_* below)
constexpr size_t O_K1B = 21626880;   // bf16 [128][64][128]
constexpr size_t O_V1B = 23724032;   // bf16 [128][64][256]
constexpr size_t O_VQT = 27918336;   // bf16 [128][128][64]  (v1@arm_q)^T
constexpr size_t O_VKT = 30015488;   // bf16 [128][128][64]
constexpr size_t O_VTB = 32112640;   // bf16 [128][64][256]  v1@arm_v
constexpr size_t O_VWT = 36306944;   // bf16 [128][256][64]  (vt@epw)^T
constexpr size_t O_Q2B = 40501248;   // bf16 [640][64][128]
constexpr size_t O_K2B = 50987008;   // bf16 [640][64][128]
constexpr size_t O_W2T = 61472768;   // bf16 [640][256][64]
constexpr size_t O_FV  = 82444288;   // f32  [640][256]  node features X
constexpr size_t O_HWS = 83099648;   // f32  [3200][256]
constexpr size_t O_EDG = 86376448;   // f32  [3200][256]
constexpr size_t O_ST  = 89653248;   // f32  [256] stats
constexpr size_t O_XA  = 89654272;
constexpr size_t O_XB  = 90309632;
constexpr size_t O_XU  = 90964992;
constexpr size_t O_XV  = 91620352;
constexpr size_t O_EE  = 92275712;
constexpr size_t O_ET  = 95552512;
constexpr size_t O_XN  = 98829312;

// WTS element offsets (bf16 elems), all stored as Wt[n][k=256]
constexpr size_t W_FAMQ = 0, W_FAMK = 32768, W_ARMQ = 65536, W_ARMK = 98304,
                 W_FAMV = 131072, W_ARMV = 196608, W_EPW = 262144;
} // namespace

// ---------- helpers ----------

DEV bhalf f2b(float f) {
  unsigned u = __float_as_uint(f);
  return (bhalf)((u + 0x7FFFu + ((u >> 16) & 1u)) >> 16);
}

DEV f4 mfma16(bf8v a, bf8v b, f4 c) {
  return __builtin_amdgcn_mfma_f32_16x16x32_bf16(a, b, c, 0, 0, 0);
}

// fragment load: lane l reads row (r0 + (l&15)), 8 contiguous k at k0 + (l>>4)*8
DEV bf8v ldfrag(const bhalf* base, int r0, int k0, int S, int l) {
  return *reinterpret_cast<const bf8v*>(base + (size_t)(r0 + (l & 15)) * S + k0 + ((l >> 4) << 3));
}

// swizzled LDS fragment load: byte = row*stride + koffB, XOR'd with ((row&7)<<4)
DEV bf8v ldswz(const bhalf* base, int row, int koffB, int strideB) {
  int byte = row * strideB + koffB;
  byte ^= ((row & 7) << 4);
  return *reinterpret_cast<const bf8v*>(reinterpret_cast<const char*>(base) + byte);
}

// in-register row softmax: sv[nt][reg], row per reg spans cols nt*16+(l&15) across 16 lanes
DEV void regSoftmax(float sv[4][4]) {
  #pragma unroll
  for (int reg = 0; reg < 4; ++reg) {
    float m = fmaxf(fmaxf(sv[0][reg], sv[1][reg]), fmaxf(sv[2][reg], sv[3][reg]));
    #pragma unroll
    for (int off = 1; off <= 8; off <<= 1) m = fmaxf(m, __shfl_xor(m, off));
    float s = 0.f;
    #pragma unroll
    for (int nt = 0; nt < 4; ++nt) { float e = __expf(sv[nt][reg] - m); sv[nt][reg] = e; s += e; }
    #pragma unroll
    for (int off = 1; off <= 8; off <<= 1) s += __shfl_xor(s, off);
    float inv = 1.f / s;
    #pragma unroll
    for (int nt = 0; nt < 4; ++nt) sv[nt][reg] *= inv;
  }
}

DEV void reduce2Atomic(float a, float b, float* ga, float* gb, float* red) {
  #pragma unroll
  for (int off = 32; off; off >>= 1) { a += __shfl_down(a, off); b += __shfl_down(b, off); }
  if ((threadIdx.x & 63) == 0) { int w = threadIdx.x >> 6; red[w*2] = a; red[w*2+1] = b; }
  __syncthreads();
  if (threadIdx.x == 0) {
    atomicAdd(ga, red[0]+red[2]+red[4]+red[6]);
    atomicAdd(gb, red[1]+red[3]+red[5]+red[7]);
  }
}

// ---------- prep kernels ----------

// transpose 7 weight matrices to bf16 Wt[n][256]
__global__ void __launch_bounds__(256) wprep(const float* fq, const float* fk, const float* fv,
                                             const float* aq, const float* ak, const float* av,
                                             const float* ep, bhalf* WT) {
  int blk = blockIdx.x, tid = threadIdx.x;
  const float* src; bhalf* dst; int N, n;
  if (blk < 512) {
    int m = blk >> 7; n = blk & 127; N = 128;
    src = (m==0)?fq:(m==1)?fk:(m==2)?aq:ak;
    dst = WT + (size_t)m*32768;
  } else {
    int r = blk - 512; int m = r >> 8; n = r & 255; N = 256;
    src = (m==0)?fv:(m==1)?av:ep;
    dst = WT + 131072 + (size_t)m*65536;
  }
  dst[(size_t)n*256 + tid] = f2b(src[(size_t)tid*N + n]);
}

// per (bt,u): transpose modality slice to bf16 Pt[64][256] (zero-pad rows) + fv means
__global__ void __launch_bounds__(256) modprep(const float* af, const float* ef, const float* gf,
                                               const float* attf, const float* sf,
                                               bhalf* PT, float* FV) {
  __shared__ float lb[49*260];
  int blk = blockIdx.x, tid = threadIdx.x;
  int u = blk % 5, bt = blk / 5, b = bt >> 4, t = bt & 15;
  const float* src = (u==0)?af:(u==1)?ef:(u==2)?gf:(u==3)?attf:sf;
  src += ((size_t)b*256*16 + t)*49;
  for (int o = tid; o < 49*256; o += TPB) {
    int c = o / 49, p = o % 49;
    lb[p*260 + c] = src[(size_t)c*784 + p];
  }
  __syncthreads();
  bhalf* pt = PT + (size_t)blk*16384;
  for (int p = 0; p < 64; ++p)
    pt[p*256 + tid] = (p < 49) ? f2b(lb[p*260 + tid]) : (bhalf)0;
  float s = 0.f;
  for (int p = 0; p < 49; ++p) s += lb[p*260 + tid];
  FV[(((size_t)(b*5+u)*16) + t)*256 + tid] = s * (1.f/49.f);
}

// ---------- MFMA GEMM chain ----------

// per bt: k1 = Paf@fam_k [64][128], v1 = Paf@fam_v [64][256]
__global__ void __launch_bounds__(256) kv1a(const bhalf* PT, const bhalf* WT,
                                            bhalf* K1B, bhalf* V1B) {
  int bt = blockIdx.x, tid = threadIdx.x, w = tid >> 6, l = tid & 63;
  const bhalf* A = PT + (size_t)bt*5*16384; // u=0 (af)
  bf8v a8[8];
  #pragma unroll
  for (int kt = 0; kt < 8; ++kt) a8[kt] = ldfrag(A, w*16, kt*32, 256, l);
  bhalf* o1 = K1B + (size_t)bt*8192;
  #pragma unroll
  for (int nt = 0; nt < 8; ++nt) {
    f4 acc = {0.f,0.f,0.f,0.f};
    #pragma unroll
    for (int kt = 0; kt < 8; ++kt)
      acc = mfma16(a8[kt], ldfrag(WT + W_FAMK, nt*16, kt*32, 256, l), acc);
    #pragma unroll
    for (int reg = 0; reg < 4; ++reg) {
      int p = w*16 + ((l>>4)<<2) + reg;
      o1[(size_t)p*128 + nt*16 + (l&15)] = f2b(acc[reg]);
    }
  }
  bhalf* o2 = V1B + (size_t)bt*16384;
  #pragma unroll
  for (int nt = 0; nt < 16; ++nt) {
    f4 acc = {0.f,0.f,0.f,0.f};
    #pragma unroll
    for (int kt = 0; kt < 8; ++kt)
      acc = mfma16(a8[kt], ldfrag(WT + W_FAMV, nt*16, kt*32, 256, l), acc);
    #pragma unroll
    for (int reg = 0; reg < 4; ++reg) {
      int p = w*16 + ((l>>4)<<2) + reg;
      o2[(size_t)p*256 + nt*16 + (l&15)] = f2b(acc[reg]);
    }
  }
}

// per bt: vqt = (v1@arm_q)^T [128][64], vkt, vtb = v1@arm_v [64][256]
__global__ void __launch_bounds__(256) kv1b(const bhalf* V1B, const bhalf* WT,
                                            bhalf* VQT, bhalf* VKT, bhalf* VTB) {
  int bt = blockIdx.x, tid = threadIdx.x, w = tid >> 6, l = tid & 63;
  const bhalf* A = V1B + (size_t)bt*16384;
  bf8v a8[8];
  #pragma unroll
  for (int kt = 0; kt < 8; ++kt) a8[kt] = ldfrag(A, w*16, kt*32, 256, l);
  bhalf* oq = VQT + (size_t)bt*8192;
  bhalf* ok = VKT + (size_t)bt*8192;
  #pragma unroll
  for (int nt = 0; nt < 8; ++nt) {
    f4 accq = {0.f,0.f,0.f,0.f}, acck = {0.f,0.f,0.f,0.f};
    #pragma unroll
    for (int kt = 0; kt < 8; ++kt) {
      accq = mfma16(a8[kt], ldfrag(WT + W_ARMQ, nt*16, kt*32, 256, l), accq);
      acck = mfma16(a8[kt], ldfrag(WT + W_ARMK, nt*16, kt*32, 256, l), acck);
    }
    #pragma unroll
    for (int reg = 0; reg < 4; ++reg) {
      int p = w*16 + ((l>>4)<<2) + reg;
      int n = nt*16 + (l&15);
      oq[(size_t)n*64 + p] = f2b(accq[reg]);   // transposed store
      ok[(size_t)n*64 + p] = f2b(acck[reg]);
    }
  }
  bhalf* ov = VTB + (size_t)bt*16384;
  #pragma unroll
  for (int nt = 0; nt < 16; ++nt) {
    f4 acc = {0.f,0.f,0.f,0.f};
    #pragma unroll
    for (int kt = 0; kt < 8; ++kt)
      acc = mfma16(a8[kt], ldfrag(WT + W_ARMV, nt*16, kt*32, 256, l), acc);
    #pragma unroll
    for (int reg = 0; reg < 4; ++reg) {
      int p = w*16 + ((l>>4)<<2) + reg;
      ov[(size_t)p*256 + nt*16 + (l&15)] = f2b(acc[reg]);
    }
  }
}

// per bt: vwt = (vt@epw)^T [256][64]
__global__ void __launch_bounds__(256) kv1c(const bhalf* VTB, const bhalf* WT, bhalf* VWT) {
  int bt = blockIdx.x, tid = threadIdx.x, w = tid >> 6, l = tid & 63;
  const bhalf* A = VTB + (size_t)bt*16384;
  bf8v a8[8];
  #pragma unroll
  for (int kt = 0; kt < 8; ++kt) a8[kt] = ldfrag(A, w*16, kt*32, 256, l);
  bhalf* ow = VWT + (size_t)bt*16384;
  #pragma unroll
  for (int nt = 0; nt < 16; ++nt) {
    f4 acc = {0.f,0.f,0.f,0.f};
    #pragma unroll
    for (int kt = 0; kt < 8; ++kt)
      acc = mfma16(a8[kt], ldfrag(WT + W_EPW, nt*16, kt*32, 256, l), acc);
    #pragma unroll
    for (int reg = 0; reg < 4; ++reg) {
      int p = w*16 + ((l>>4)<<2) + reg;
      ow[(size_t)(nt*16 + (l&15))*64 + p] = f2b(acc[reg]);  // transposed
    }
  }
}

// ---------- stage 1: FAM attention + ARM input projections ----------
// per (bt,u): q1 = Pt@fam_q; P = softmax(q1 k1^T * s); q2 = P@vq, k2 = P@vk, w2t = (P@vw)^T
__global__ void __launch_bounds__(256) s1ker(const bhalf* PT, const bhalf* WT,
    const bhalf* K1B, const bhalf* VQT, const bhalf* VKT, const bhalf* VWT,
    bhalf* Q2B, bhalf* K2B, bhalf* W2T)
{
  __shared__ bhalf bufA[64*280];  // q1 staging, then w2 staging
  __shared__ bhalf bufP[64*72];
  int blk = blockIdx.x;           // bt*5 + u
  int bt = blk / 5;
  int tid = threadIdx.x, w = tid >> 6, l = tid & 63;
  const bhalf* Pt = PT + (size_t)blk*16384;
  // phase 1: q1 (M=64, N=128, K=256) -> bufA bf16
  {
    bf8v a8[8];
    #pragma unroll
    for (int kt = 0; kt < 8; ++kt) a8[kt] = ldfrag(Pt, w*16, kt*32, 256, l);
    #pragma unroll
    for (int nt = 0; nt < 8; ++nt) {
      f4 acc = {0.f,0.f,0.f,0.f};
      #pragma unroll
      for (int kt = 0; kt < 8; ++kt)
        acc = mfma16(a8[kt], ldfrag(WT + W_FAMQ, nt*16, kt*32, 256, l), acc);
      #pragma unroll
      for (int reg = 0; reg < 4; ++reg)
        bufA[(w*16 + ((l>>4)<<2) + reg)*280 + nt*16 + (l&15)] = f2b(acc[reg]);
    }
  }
  __syncthreads();
  // phase 2: scores vs k1 (own-wave rows from bufA), softmax in regs
  float sv[4][4];
  {
    const bhalf* K1 = K1B + (size_t)bt*8192;
    bf8v aq[4];
    #pragma unroll
    for (int kt = 0; kt < 4; ++kt) aq[kt] = ldfrag(bufA, w*16, kt*32, 280, l);
    #pragma unroll
    for (int nt = 0; nt < 4; ++nt) {
      f4 acc = {0.f,0.f,0.f,0.f};
      #pragma unroll
      for (int kt = 0; kt < 4; ++kt)
        acc = mfma16(aq[kt], ldfrag(K1, nt*16, kt*32, 128, l), acc);
      #pragma unroll
      for (int reg = 0; reg < 4; ++reg) sv[nt][reg] = acc[reg] * ATT_SCALE;
    }
  }
  if ((l & 15) > 0) { sv[3][0] = -1e30f; sv[3][1] = -1e30f; sv[3][2] = -1e30f; sv[3][3] = -1e30f; }
  regSoftmax(sv);
  #pragma unroll
  for (int nt = 0; nt < 4; ++nt)
    #pragma unroll
    for (int reg = 0; reg < 4; ++reg)
      bufP[(w*16 + ((l>>4)<<2) + reg)*72 + nt*16 + (l&15)] = f2b(sv[nt][reg]);
  __syncthreads();
  // phase 3: PVs
  bf8v ap0 = ldfrag(bufP, w*16, 0, 72, l);
  bf8v ap1 = ldfrag(bufP, w*16, 32, 72, l);
  {
    const bhalf* vq = VQT + (size_t)bt*8192;
    bhalf* q2 = Q2B + (size_t)blk*8192;
    #pragma unroll
    for (int nt = 0; nt < 8; ++nt) {
      f4 acc = {0.f,0.f,0.f,0.f};
      acc = mfma16(ap0, ldfrag(vq, nt*16, 0, 64, l), acc);
      acc = mfma16(ap1, ldfrag(vq, nt*16, 32, 64, l), acc);
      #pragma unroll
      for (int reg = 0; reg < 4; ++reg) {
        int p = w*16 + ((l>>4)<<2) + reg;
        q2[(size_t)p*128 + nt*16 + (l&15)] = (p < 49) ? f2b(acc[reg]) : (bhalf)0;
      }
    }
  }
  {
    const bhalf* vk = VKT + (size_t)bt*8192;
    bhalf* k2 = K2B + (size_t)blk*8192;
    #pragma unroll
    for (int nt = 0; nt < 8; ++nt) {
      f4 acc = {0.f,0.f,0.f,0.f};
      acc = mfma16(ap0, ldfrag(vk, nt*16, 0, 64, l), acc);
      acc = mfma16(ap1, ldfrag(vk, nt*16, 32, 64, l), acc);
      #pragma unroll
      for (int reg = 0; reg < 4; ++reg) {
        int p = w*16 + ((l>>4)<<2) + reg;
        k2[(size_t)p*128 + nt*16 + (l&15)] = (p < 49) ? f2b(acc[reg]) : (bhalf)0;
      }
    }
  }
  {
    const bhalf* vw = VWT + (size_t)bt*16384;
    #pragma unroll
    for (int nt = 0; nt < 16; ++nt) {
      f4 acc = {0.f,0.f,0.f,0.f};
      acc = mfma16(ap0, ldfrag(vw, nt*16, 0, 64, l), acc);
      acc = mfma16(ap1, ldfrag(vw, nt*16, 32, 64, l), acc);
      #pragma unroll
      for (int reg = 0; reg < 4; ++reg)
        bufA[(w*16 + ((l>>4)<<2) + reg)*280 + nt*16 + (l&15)] = f2b(acc[reg]);
    }
  }
  __syncthreads();
  // epilogue: w2t[c][r] coalesced (pairs packed into u32)
  unsigned* wt = reinterpret_cast<unsigned*>(W2T + (size_t)blk*16384);
  for (int it = 0; it < 32; ++it) {
    int o = it*256 + tid;       // 0..8191
    int c = o >> 5, ii = o & 31;
    int r0 = ii*2;
    unsigned lo = (r0   < 49) ? (unsigned)bufA[r0*280 + c]     : 0u;
    unsigned hi = (r0+1 < 49) ? (unsigned)bufA[(r0+1)*280 + c] : 0u;
    wt[o] = lo | (hi << 16);
  }
}

// ---------- stage 2: ARM attention + edge stats (edge tensor never materializes) ----------
// Restructured: one block per (bt, i). K_i/V_i staged to LDS once (XOR-swizzled),
// loop j=0..4 computes edges e=i*5+j. XCD-bijective blockIdx swizzle groups the
// 5 same-bt blocks (which share the 5 Q_j slices) onto one XCD for L2 reuse.
__global__ void __launch_bounds__(256) s2ker(const bhalf* Q2B, const bhalf* K2B, const bhalf* W2T,
    const float* epb, float* hws, float* gs1, float* gs2)
{
  __shared__ bhalf Kl[64*128];    // 16 KB, swizzled rows of 256 B
  __shared__ bhalf Vl[256*64];    // 32 KB, swizzled rows of 128 B
  __shared__ bhalf bufP[64*72];
  __shared__ float redH[4*256];
  __shared__ float redS[8];
  int orig = blockIdx.x;
  int blk = (orig & 7) * 80 + (orig >> 3);   // 640 = 8*80, bijective XCD grouping
  int i = blk % 5, bt = blk / 5, b = bt >> 4, t = bt & 15;
  int tid = threadIdx.x, w = tid >> 6, l = tid & 63;
  const bhalf* K = K2B + (size_t)(bt*5 + i)*8192;
  const bhalf* V = W2T + (size_t)(bt*5 + i)*16384;
  // ---- stage K (16 KB) and V (32 KB): coalesced global read, swizzled LDS write ----
  // LDS[x ^ ((row(x)&7)<<4)] = G[x]; read side applies the same involution.
  {
    const char* gk = reinterpret_cast<const char*>(K);
    const char* gv = reinterpret_cast<const char*>(V);
    char* lk = reinterpret_cast<char*>(Kl);
    char* lv = reinterpret_cast<char*>(Vl);
    #pragma unroll
    for (int c = 0; c < 4; ++c) {
      int x = (c*256 + tid) << 4;                 // K: row = x>>8 (256 B rows)
      float4 val = *reinterpret_cast<const float4*>(gk + x);
      *reinterpret_cast<float4*>(lk + (x ^ (((x >> 8) & 7) << 4))) = val;
    }
    #pragma unroll
    for (int c = 0; c < 8; ++c) {
      int x = (c*256 + tid) << 4;                 // V: row = x>>7 (128 B rows)
      float4 val = *reinterpret_cast<const float4*>(gv + x);
      *reinterpret_cast<float4*>(lv + (x ^ (((x >> 7) & 7) << 4))) = val;
    }
  }
  __syncthreads();

  for (int j = 0; j < 5; ++j) {
    int e = i*5 + j;
    const bhalf* Q = Q2B + (size_t)(bt*5 + j)*8192;
    float sv[4][4];
    {
      bf8v aq[4];
      #pragma unroll
      for (int kt = 0; kt < 4; ++kt) aq[kt] = ldfrag(Q, w*16, kt*32, 128, l);
      #pragma unroll
      for (int nt = 0; nt < 4; ++nt) {
        f4 acc = {0.f,0.f,0.f,0.f};
        #pragma unroll
        for (int kt = 0; kt < 4; ++kt)
          acc = mfma16(aq[kt], ldswz(Kl, nt*16 + (l & 15), kt*64 + ((l >> 4) << 4), 256), acc);
        #pragma unroll
        for (int reg = 0; reg < 4; ++reg) sv[nt][reg] = acc[reg] * ATT_SCALE;
      }
    }
    if ((l & 15) > 0) { sv[3][0] = -1e30f; sv[3][1] = -1e30f; sv[3][2] = -1e30f; sv[3][3] = -1e30f; }
    regSoftmax(sv);
    #pragma unroll
    for (int nt = 0; nt < 4; ++nt)
      #pragma unroll
      for (int reg = 0; reg < 4; ++reg)
        bufP[(w*16 + ((l>>4)<<2) + reg)*72 + nt*16 + (l&15)] = f2b(sv[nt][reg]);
    __syncthreads();   // B1 (also guards redS of previous j vs nothing; bufP ready)
    bf8v ap0 = ldfrag(bufP, w*16, 0, 72, l);
    bf8v ap1 = ldfrag(bufP, w*16, 32, 72, l);
    float sqa = 0.f;
    #pragma unroll
    for (int nt2 = 0; nt2 < 16; ++nt2) {
      f4 acc = {0.f,0.f,0.f,0.f};
      acc = mfma16(ap0, ldswz(Vl, nt2*16 + (l & 15), ((l >> 4) << 4), 128), acc);
      acc = mfma16(ap1, ldswz(Vl, nt2*16 + (l & 15), 64 + ((l >> 4) << 4), 128), acc);
      int c = nt2*16 + (l & 15);
      float bias = epb[c];
      float hw = 0.f;
      #pragma unroll
      for (int reg = 0; reg < 4; ++reg) {
        int p = w*16 + ((l>>4)<<2) + reg;
        if (p < 49) { float v = acc[reg] + bias; hw += v; sqa += v*v; }
      }
      hw += __shfl_xor(hw, 16);
      hw += __shfl_xor(hw, 32);
      if ((l >> 4) == 0) redH[w*256 + c] = hw;
    }
    __syncthreads();   // B2: redH complete
    float hwtot = redH[tid] + redH[256+tid] + redH[512+tid] + redH[768+tid];
    hws[(((size_t)(b*25+e)*16) + t)*256 + tid] = hwtot;
    float g1 = hwtot;
    #pragma unroll
    for (int off = 32; off; off >>= 1) { g1 += __shfl_down(g1, off); sqa += __shfl_down(sqa, off); }
    if (l == 0) { redS[w*2] = g1; redS[w*2+1] = sqa; }
    __syncthreads();   // B3: redS complete; also WAR-guards redH/bufP for next j
    if (tid == 0) {
      atomicAdd(gs1 + e, redS[0]+redS[2]+redS[4]+redS[6]);
      atomicAdd(gs2 + e, redS[1]+redS[3]+redS[5]+redS[7]);
    }
  }
}

// f_e = gem-BN applied to hw-mean
__global__ void __launch_bounds__(256) s2finker(const float* hws, const float* gs1, const float* gs2,
                                                const float* gg, const float* gb, float* EDG) {
  int blk = blockIdx.x;
  int e = (blk >> 4) % 25;
  size_t idx = (size_t)blk*256 + threadIdx.x;
  constexpr float invCnt = 1.f/1605632.f;
  float m = gs1[e]*invCnt;
  float var = gs2[e]*invCnt - m*m;
  float rstd = rsqrtf(var + 1e-5f);
  EDG[idx] = gg[e]*((hws[idx]*(1.f/49.f) - m)*rstd) + gb[e];
}

// ---------- GNN kernels (f32, unchanged) ----------

__global__ void __launch_bounds__(256) gnnProj(const float* X, const float* EDG,
    const float* Wa, const float* Wb, const float* Wu, const float* Wv, const float* We,
    float* xA, float* xB, float* xU, float* xV, float* eE) {
  int blk = blockIdx.x, tid = threadIdx.x;
  const float* src; const float* W; float* dst; int r0;
  if (blk < 160) {
    int m = blk / 40; r0 = (blk % 40) * 16;
    src = X;
    W   = (m==0)?Wa:(m==1)?Wb:(m==2)?Wu:Wv;
    dst = (m==0)?xA:(m==1)?xB:(m==2)?xU:xV;
  } else { r0 = (blk-160)*16; src = EDG; W = We; dst = eE; }
  float acc[16];
  #pragma unroll
  for (int r = 0; r < 16; ++r) acc[r] = 0.f;
  for (int c = 0; c < 256; c += 4) {
    float w0 = W[(size_t)(c+0)*256 + tid];
    float w1 = W[(size_t)(c+1)*256 + tid];
    float w2 = W[(size_t)(c+2)*256 + tid];
    float w3 = W[(size_t)(c+3)*256 + tid];
    #pragma unroll
    for (int r = 0; r < 16; ++r) {
      float4 a = *reinterpret_cast<const float4*>(&src[(size_t)(r0+r)*256 + c]);
      acc[r] += a.x*w0 + a.y*w1 + a.z*w2 + a.w*w3;
    }
  }
  #pragma unroll
  for (int r = 0; r < 16; ++r) dst[(size_t)(r0+r)*256 + tid] = acc[r];
}

__global__ void __launch_bounds__(256) g2a(const float* xA, const float* xB, const float* eE,
                                           float* ET, float* s1, float* s2) {
  __shared__ float red[8];
  int blk = blockIdx.x, tid = threadIdx.x;
  int b = blk / 400, e = (blk >> 4) % 25, t = blk & 15;
  int i = e / 5, j = e % 5;
  size_t ni = ((size_t)(b*5+i)*16 + t)*256 + tid;
  size_t nj = ((size_t)(b*5+j)*16 + t)*256 + tid;
  size_t ee = (size_t)blk*256 + tid;
  float v = xA[ni] + xB[nj] + eE[ee];
  ET[ee] = v;
  reduce2Atomic(v, v*v, s1 + e, s2 + e, red);
}

__global__ void __launch_bounds__(256) g2b(const float* ET, float* EDG, const float* g, const float* bb,
                                           const float* s1, const float* s2) {
  int blk = blockIdx.x, tid = threadIdx.x;
  int e = (blk >> 4) % 25;
  size_t ee = (size_t)blk*256 + tid;
  constexpr float invCnt = 1.f/32768.f;
  float m = s1[e]*invCnt;
  float var = s2[e]*invCnt - m*m;
  float rstd = rsqrtf(var + 1e-5f);
  float v = g[e]*((ET[ee]-m)*rstd) + bb[e];
  if (v != v) v = 0.f;
  EDG[ee] += fmaxf(v, 0.f);
}

__global__ void __launch_bounds__(256) g3a(const float* EDG, const float* xV, const float* xU,
                                           float* XN, float* s1, float* s2) {
  __shared__ float red[8];
  int blk = blockIdx.x, tid = threadIdx.x;
  int b = blk / 80, i = (blk >> 4) % 5, t = blk & 15;
  float ex[5]; float ssum = 0.f;
  #pragma unroll
  for (int j = 0; j < 5; ++j) {
    float ev = EDG[((size_t)(b*25 + i*5 + j)*16 + t)*256 + tid];
    float sg = 1.f/(1.f + __expf(-ev));
    ex[j] = __expf(sg);
    ssum += ex[j];
  }
  float inv = 1.f/ssum;
  float agg = 0.f;
  #pragma unroll
  for (int j = 0; j < 5; ++j)
    agg += ex[j]*inv * xV[((size_t)(b*5+j)*16 + t)*256 + tid];
  agg *= 0.2f;
  size_t ni = (size_t)blk*256 + tid;
  float xn = xU[ni] + agg;
  XN[ni] = xn;
  reduce2Atomic(xn, xn*xn, s1 + i, s2 + i, red);
}

__global__ void __launch_bounds__(256) g3b(const float* XN, float* X, const float* g, const float* bb,
                                           const float* s1, const float* s2, int mask) {
  int blk = blockIdx.x, tid = threadIdx.x;
  int i = (blk >> 4) % 5;
  size_t ni = (size_t)blk*256 + tid;
  constexpr float invCnt = 1.f/32768.f;
  float m = s1[i]*invCnt;
  float var = s2[i]*invCnt - m*m;
  float rstd = rsqrtf(var + 1e-5f);
  float v = g[i]*((XN[ni]-m)*rstd) + bb[i];
  if (mask && v != v) v = 0.f;
  X[ni] = fmaxf(X[ni] + v, 0.f);
}

__global__ void __launch_bounds__(256) finker(const float* X, const float* EDG,
                                              const float* sc, const float* efw, const float* efb,
                                              float* out) {
  __shared__ float red[12];
  int blk = blockIdx.x, tid = threadIdx.x;
  if (blk < 640) {
    int nn = (blk >> 4) % 5;
    float x = X[(size_t)blk*256 + tid];
    float s = fmaxf(sc[nn*256 + tid], 0.f);
    float xx = x*x, ss = s*s, xs = x*s;
    #pragma unroll
    for (int off = 32; off; off >>= 1) {
      xx += __shfl_down(xx, off); ss += __shfl_down(ss, off); xs += __shfl_down(xs, off);
    }
    if ((tid & 63) == 0) { int w = tid >> 6; red[w*3] = xx; red[w*3+1] = ss; red[w*3+2] = xs; }
    __syncthreads();
    if (tid == 0) {
      float sxx = red[0]+red[3]+red[6]+red[9];
      float sss = red[1]+red[4]+red[7]+red[10];
      float sxs = red[2]+red[5]+red[8]+red[11];
      float nx = fmaxf(sqrtf(sxx), 1e-12f);
      float ns = fmaxf(sqrtf(sss), 1e-12f);
      out[blk] = sxs / (nx * ns);
    }
  } else {
    int eb = blk - 640;
    float v = EDG[(size_t)eb*256 + tid] * efw[tid];
    #pragma unroll
    for (int off = 32; off; off >>= 1) v += __shfl_down(v, off);
    if ((tid & 63) == 0) red[tid >> 6] = v;
    __syncthreads();
    if (tid == 0) out[640 + eb] = red[0]+red[1]+red[2]+red[3] + efb[0];
  }
}

// ---------- host ----------

extern "C" void kernel_launch(void* const* d_in, const int* in_sizes, int n_in,
                              void* d_out, int out_size, void* d_ws, size_t ws_size,
                              hipStream_t stream) {
  (void)in_sizes; (void)n_in; (void)out_size; (void)ws_size;
  const float* af    = (const float*)d_in[0];
  const float* ef    = (const float*)d_in[1];
  const float* gfm   = (const float*)d_in[2];
  const float* attf  = (const float*)d_in[3];
  const float* sfm   = (const float*)d_in[4];
  const float* fam_q = (const float*)d_in[5];
  const float* fam_k = (const float*)d_in[6];
  const float* fam_v = (const float*)d_in[7];
  const float* arm_q = (const float*)d_in[8];
  const float* arm_k = (const float*)d_in[9];
  const float* arm_v = (const float*)d_in[10];
  const float* epw   = (const float*)d_in[11];
  const float* epb   = (const float*)d_in[12];
  const float* gemg  = (const float*)d_in[13];
  const float* gemb  = (const float*)d_in[14];
  const float* Us[2]   = {(const float*)d_in[15], (const float*)d_in[20]};
  const float* Vs[2]   = {(const float*)d_in[16], (const float*)d_in[21]};
  const float* As[2]   = {(const float*)d_in[17], (const float*)d_in[22]};
  const float* Bs[2]   = {(const float*)d_in[18], (const float*)d_in[23]};
  const float* Es[2]   = {(const float*)d_in[19], (const float*)d_in[24]};
  const float* bnvg[2] = {(const float*)d_in[25], (const float*)d_in[29]};
  const float* bnvb[2] = {(const float*)d_in[26], (const float*)d_in[30]};
  const float* bneg[2] = {(const float*)d_in[27], (const float*)d_in[31]};
  const float* bneb[2] = {(const float*)d_in[28], (const float*)d_in[32]};
  const float* scp  = (const float*)d_in[33];
  const float* efw  = (const float*)d_in[34];
  const float* efb  = (const float*)d_in[35];

  char* ws = (char*)d_ws;
  bhalf* PT  = (bhalf*)(ws + O_PT);
  bhalf* WTS = (bhalf*)(ws + O_WTS);
  bhalf* K1B = (bhalf*)(ws + O_K1B);
  bhalf* V1B = (bhalf*)(ws + O_V1B);
  bhalf* VQT = (bhalf*)(ws + O_VQT);
  bhalf* VKT = (bhalf*)(ws + O_VKT);
  bhalf* VTB = (bhalf*)(ws + O_VTB);
  bhalf* VWT = (bhalf*)(ws + O_VWT);
  bhalf* Q2B = (bhalf*)(ws + O_Q2B);
  bhalf* K2B = (bhalf*)(ws + O_K2B);
  bhalf* W2T = (bhalf*)(ws + O_W2T);
  float* FV  = (float*)(ws + O_FV);
  float* HWS = (float*)(ws + O_HWS);
  float* EDG = (float*)(ws + O_EDG);
  float* st  = (float*)(ws + O_ST);
  float* XA  = (float*)(ws + O_XA);
  float* XB  = (float*)(ws + O_XB);
  float* XU  = (float*)(ws + O_XU);
  float* XV  = (float*)(ws + O_XV);
  float* EE  = (float*)(ws + O_EE);
  float* ET  = (float*)(ws + O_ET);
  float* XN  = (float*)(ws + O_XN);

  hipMemsetAsync(st, 0, 256*sizeof(float), stream);

  wprep<<<1280, TPB, 0, stream>>>(fam_q, fam_k, fam_v, arm_q, arm_k, arm_v, epw, WTS);
  modprep<<<640, TPB, 0, stream>>>(af, ef, gfm, attf, sfm, PT, FV);
  kv1a<<<128, TPB, 0, stream>>>(PT, WTS, K1B, V1B);
  kv1b<<<128, TPB, 0, stream>>>(V1B, WTS, VQT, VKT, VTB);
  kv1c<<<128, TPB, 0, stream>>>(VTB, WTS, VWT);
  s1ker<<<640, TPB, 0, stream>>>(PT, WTS, K1B, VQT, VKT, VWT, Q2B, K2B, W2T);
  s2ker<<<640, TPB, 0, stream>>>(Q2B, K2B, W2T, epb, HWS, st+0, st+25);
  s2finker<<<3200, TPB, 0, stream>>>(HWS, st+0, st+25, gemg, gemb, EDG);

  for (int L = 0; L < 2; ++L) {
    float* es1 = st + 64 + L*64;
    float* es2 = es1 + 25;
    float* ns1 = es1 + 50;
    float* ns2 = es1 + 55;
    gnnProj<<<360, TPB, 0, stream>>>(FV, EDG, As[L], Bs[L], Us[L], Vs[L], Es[L],
                                     XA, XB, XU, XV, EE);
    g2a<<<3200, TPB, 0, stream>>>(XA, XB, EE, ET, es1, es2);
    g2b<<<3200, TPB, 0, stream>>>(ET, EDG, bneg[L], bneb[L], es1, es2);
    g3a<<<640, TPB, 0, stream>>>(EDG, XV, XU, XN, ns1, ns2);
    g3b<<<640, TPB, 0, stream>>>(XN, FV, bnvg[L], bnvb[L], ns1, ns2, L == 0 ? 1 : 0);
  }

  finker<<<3840, TPB, 0, stream>>>(FV, EDG, scp, efw, efb, (float*)d_out);
}

// Round 2
// 478.668 us; speedup vs baseline: 1.1291x; 1.0371x over previous
//
#include <hip/hip_runtime.h>

#define DEV __device__ __forceinline__

typedef unsigned short bhalf;
typedef __attribute__((ext_vector_type(8))) short bf8v;
typedef __attribute__((ext_vector_type(4))) float f4;

namespace {
constexpr int TPB = 256;
constexpr float ATT_SCALE = 0.08838834764831845f; // 1/sqrt(128)

// ---- workspace byte offsets ----
constexpr size_t O_PT  = 0;          // bf16 [640][64][256]  modalities, zero-pad rows
constexpr size_t O_WTS = 20971520;   // bf16 transposed weights (see W_* below)
constexpr size_t O_K1B = 21626880;   // bf16 [128][64][128]
constexpr size_t O_V1B = 23724032;   // bf16 [128][64][256]
constexpr size_t O_VQT = 27918336;   // bf16 [128][128][64]  (v1@arm_q)^T
constexpr size_t O_VKT = 30015488;   // bf16 [128][128][64]
constexpr size_t O_VTB = 32112640;   // bf16 [128][64][256]  v1@arm_v
constexpr size_t O_VWT = 36306944;   // bf16 [128][256][64]  (vt@epw)^T
constexpr size_t O_Q2B = 40501248;   // bf16 [640][64][128]
constexpr size_t O_K2B = 50987008;   // bf16 [640][64][128]
constexpr size_t O_W2T = 61472768;   // bf16 [640][256][64]
constexpr size_t O_FV  = 82444288;   // f32  [640][256]  node features X
constexpr size_t O_HWS = 83099648;   // f32  [3200][256]
constexpr size_t O_EDG = 86376448;   // f32  [3200][256]
constexpr size_t O_ST  = 89653248;   // f32  [256] stats
constexpr size_t O_XA  = 89654272;
constexpr size_t O_XB  = 90309632;
constexpr size_t O_XU  = 90964992;
constexpr size_t O_XV  = 91620352;
constexpr size_t O_EE  = 92275712;
constexpr size_t O_ET  = 95552512;
constexpr size_t O_XN  = 98829312;

// WTS element offsets (bf16 elems), all stored as Wt[n][k=256]
constexpr size_t W_FAMQ = 0, W_FAMK = 32768, W_ARMQ = 65536, W_ARMK = 98304,
                 W_FAMV = 131072, W_ARMV = 196608, W_EPW = 262144;
} // namespace

// ---------- helpers ----------

DEV bhalf f2b(float f) {
  unsigned u = __float_as_uint(f);
  return (bhalf)((u + 0x7FFFu + ((u >> 16) & 1u)) >> 16);
}

DEV f4 mfma16(bf8v a, bf8v b, f4 c) {
  return __builtin_amdgcn_mfma_f32_16x16x32_bf16(a, b, c, 0, 0, 0);
}

// fragment load: lane l reads row (r0 + (l&15)), 8 contiguous k at k0 + (l>>4)*8
DEV bf8v ldfrag(const bhalf* base, int r0, int k0, int S, int l) {
  return *reinterpret_cast<const bf8v*>(base + (size_t)(r0 + (l & 15)) * S + k0 + ((l >> 4) << 3));
}

// swizzled LDS fragment load: byte = row*stride + koffB, XOR'd with ((row&7)<<4)
DEV bf8v ldswz(const bhalf* base, int row, int koffB, int strideB) {
  int byte = row * strideB + koffB;
  byte ^= ((row & 7) << 4);
  return *reinterpret_cast<const bf8v*>(reinterpret_cast<const char*>(base) + byte);
}

// in-register row softmax: sv[nt][reg], row per reg spans cols nt*16+(l&15) across 16 lanes
DEV void regSoftmax(float sv[4][4]) {
  #pragma unroll
  for (int reg = 0; reg < 4; ++reg) {
    float m = fmaxf(fmaxf(sv[0][reg], sv[1][reg]), fmaxf(sv[2][reg], sv[3][reg]));
    #pragma unroll
    for (int off = 1; off <= 8; off <<= 1) m = fmaxf(m, __shfl_xor(m, off));
    float s = 0.f;
    #pragma unroll
    for (int nt = 0; nt < 4; ++nt) { float e = __expf(sv[nt][reg] - m); sv[nt][reg] = e; s += e; }
    #pragma unroll
    for (int off = 1; off <= 8; off <<= 1) s += __shfl_xor(s, off);
    float inv = 1.f / s;
    #pragma unroll
    for (int nt = 0; nt < 4; ++nt) sv[nt][reg] *= inv;
  }
}

DEV void reduce2Atomic(float a, float b, float* ga, float* gb, float* red) {
  #pragma unroll
  for (int off = 32; off; off >>= 1) { a += __shfl_down(a, off); b += __shfl_down(b, off); }
  if ((threadIdx.x & 63) == 0) { int w = threadIdx.x >> 6; red[w*2] = a; red[w*2+1] = b; }
  __syncthreads();
  if (threadIdx.x == 0) {
    atomicAdd(ga, red[0]+red[2]+red[4]+red[6]);
    atomicAdd(gb, red[1]+red[3]+red[5]+red[7]);
  }
}

// ---------- prep kernels ----------

// transpose 7 weight matrices to bf16 Wt[n][256]
__global__ void __launch_bounds__(256) wprep(const float* fq, const float* fk, const float* fv,
                                             const float* aq, const float* ak, const float* av,
                                             const float* ep, bhalf* WT) {
  int blk = blockIdx.x, tid = threadIdx.x;
  const float* src; bhalf* dst; int N, n;
  if (blk < 512) {
    int m = blk >> 7; n = blk & 127; N = 128;
    src = (m==0)?fq:(m==1)?fk:(m==2)?aq:ak;
    dst = WT + (size_t)m*32768;
  } else {
    int r = blk - 512; int m = r >> 8; n = r & 255; N = 256;
    src = (m==0)?fv:(m==1)?av:ep;
    dst = WT + 131072 + (size_t)m*65536;
  }
  dst[(size_t)n*256 + tid] = f2b(src[(size_t)tid*N + n]);
}

// per (bt,u): transpose modality slice to bf16 Pt[64][256] (zero-pad rows) + fv means
__global__ void __launch_bounds__(256) modprep(const float* af, const float* ef, const float* gf,
                                               const float* attf, const float* sf,
                                               bhalf* PT, float* FV) {
  __shared__ float lb[49*260];
  int blk = blockIdx.x, tid = threadIdx.x;
  int u = blk % 5, bt = blk / 5, b = bt >> 4, t = bt & 15;
  const float* src = (u==0)?af:(u==1)?ef:(u==2)?gf:(u==3)?attf:sf;
  src += ((size_t)b*256*16 + t)*49;
  for (int o = tid; o < 49*256; o += TPB) {
    int c = o / 49, p = o % 49;
    lb[p*260 + c] = src[(size_t)c*784 + p];
  }
  __syncthreads();
  bhalf* pt = PT + (size_t)blk*16384;
  for (int p = 0; p < 64; ++p)
    pt[p*256 + tid] = (p < 49) ? f2b(lb[p*260 + tid]) : (bhalf)0;
  float s = 0.f;
  for (int p = 0; p < 49; ++p) s += lb[p*260 + tid];
  FV[(((size_t)(b*5+u)*16) + t)*256 + tid] = s * (1.f/49.f);
}

// ---------- MFMA GEMM chain (nt-split over blockIdx.y for parallelism) ----------

// per (bt, part): part0: k1 = Paf@fam_k [64][128]; part1/2: v1 = Paf@fam_v halves
__global__ void __launch_bounds__(256) kv1a(const bhalf* PT, const bhalf* WT,
                                            bhalf* K1B, bhalf* V1B) {
  int bt = blockIdx.x, part = blockIdx.y;
  int tid = threadIdx.x, w = tid >> 6, l = tid & 63;
  const bhalf* A = PT + (size_t)bt*5*16384; // u=0 (af)
  bf8v a8[8];
  #pragma unroll
  for (int kt = 0; kt < 8; ++kt) a8[kt] = ldfrag(A, w*16, kt*32, 256, l);
  if (part == 0) {
    bhalf* o1 = K1B + (size_t)bt*8192;
    #pragma unroll
    for (int nt = 0; nt < 8; ++nt) {
      f4 acc = {0.f,0.f,0.f,0.f};
      #pragma unroll
      for (int kt = 0; kt < 8; ++kt)
        acc = mfma16(a8[kt], ldfrag(WT + W_FAMK, nt*16, kt*32, 256, l), acc);
      #pragma unroll
      for (int reg = 0; reg < 4; ++reg) {
        int p = w*16 + ((l>>4)<<2) + reg;
        o1[(size_t)p*128 + nt*16 + (l&15)] = f2b(acc[reg]);
      }
    }
  } else {
    bhalf* o2 = V1B + (size_t)bt*16384;
    int nt0 = (part - 1) * 8;
    #pragma unroll
    for (int nn = 0; nn < 8; ++nn) {
      int nt = nt0 + nn;
      f4 acc = {0.f,0.f,0.f,0.f};
      #pragma unroll
      for (int kt = 0; kt < 8; ++kt)
        acc = mfma16(a8[kt], ldfrag(WT + W_FAMV, nt*16, kt*32, 256, l), acc);
      #pragma unroll
      for (int reg = 0; reg < 4; ++reg) {
        int p = w*16 + ((l>>4)<<2) + reg;
        o2[(size_t)p*256 + nt*16 + (l&15)] = f2b(acc[reg]);
      }
    }
  }
}

// per (bt, part): part0: vqt/vkt transposed [128][64]; part1/2: vtb = v1@arm_v halves
__global__ void __launch_bounds__(256) kv1b(const bhalf* V1B, const bhalf* WT,
                                            bhalf* VQT, bhalf* VKT, bhalf* VTB) {
  int bt = blockIdx.x, part = blockIdx.y;
  int tid = threadIdx.x, w = tid >> 6, l = tid & 63;
  const bhalf* A = V1B + (size_t)bt*16384;
  bf8v a8[8];
  #pragma unroll
  for (int kt = 0; kt < 8; ++kt) a8[kt] = ldfrag(A, w*16, kt*32, 256, l);
  if (part == 0) {
    bhalf* oq = VQT + (size_t)bt*8192;
    bhalf* ok = VKT + (size_t)bt*8192;
    #pragma unroll
    for (int nt = 0; nt < 8; ++nt) {
      f4 accq = {0.f,0.f,0.f,0.f}, acck = {0.f,0.f,0.f,0.f};
      #pragma unroll
      for (int kt = 0; kt < 8; ++kt) {
        accq = mfma16(a8[kt], ldfrag(WT + W_ARMQ, nt*16, kt*32, 256, l), accq);
        acck = mfma16(a8[kt], ldfrag(WT + W_ARMK, nt*16, kt*32, 256, l), acck);
      }
      #pragma unroll
      for (int reg = 0; reg < 4; ++reg) {
        int p = w*16 + ((l>>4)<<2) + reg;
        int n = nt*16 + (l&15);
        oq[(size_t)n*64 + p] = f2b(accq[reg]);   // transposed store
        ok[(size_t)n*64 + p] = f2b(acck[reg]);
      }
    }
  } else {
    bhalf* ov = VTB + (size_t)bt*16384;
    int nt0 = (part - 1) * 8;
    #pragma unroll
    for (int nn = 0; nn < 8; ++nn) {
      int nt = nt0 + nn;
      f4 acc = {0.f,0.f,0.f,0.f};
      #pragma unroll
      for (int kt = 0; kt < 8; ++kt)
        acc = mfma16(a8[kt], ldfrag(WT + W_ARMV, nt*16, kt*32, 256, l), acc);
      #pragma unroll
      for (int reg = 0; reg < 4; ++reg) {
        int p = w*16 + ((l>>4)<<2) + reg;
        ov[(size_t)p*256 + nt*16 + (l&15)] = f2b(acc[reg]);
      }
    }
  }
}

// per (bt, part): vwt = (vt@epw)^T [256][64], nt halves
__global__ void __launch_bounds__(256) kv1c(const bhalf* VTB, const bhalf* WT, bhalf* VWT) {
  int bt = blockIdx.x, part = blockIdx.y;
  int tid = threadIdx.x, w = tid >> 6, l = tid & 63;
  const bhalf* A = VTB + (size_t)bt*16384;
  bf8v a8[8];
  #pragma unroll
  for (int kt = 0; kt < 8; ++kt) a8[kt] = ldfrag(A, w*16, kt*32, 256, l);
  bhalf* ow = VWT + (size_t)bt*16384;
  int nt0 = part * 8;
  #pragma unroll
  for (int nn = 0; nn < 8; ++nn) {
    int nt = nt0 + nn;
    f4 acc = {0.f,0.f,0.f,0.f};
    #pragma unroll
    for (int kt = 0; kt < 8; ++kt)
      acc = mfma16(a8[kt], ldfrag(WT + W_EPW, nt*16, kt*32, 256, l), acc);
    #pragma unroll
    for (int reg = 0; reg < 4; ++reg) {
      int p = w*16 + ((l>>4)<<2) + reg;
      ow[(size_t)(nt*16 + (l&15))*64 + p] = f2b(acc[reg]);  // transposed
    }
  }
}

// ---------- stage 1: FAM attention + ARM input projections ----------
// per (bt,u): q1 = Pt@fam_q; P = softmax(q1 k1^T * s); q2 = P@vq, k2 = P@vk, w2t = (P@vw)^T
__global__ void __launch_bounds__(256) s1ker(const bhalf* PT, const bhalf* WT,
    const bhalf* K1B, const bhalf* VQT, const bhalf* VKT, const bhalf* VWT,
    bhalf* Q2B, bhalf* K2B, bhalf* W2T)
{
  __shared__ bhalf bufA[64*280];  // q1 staging, then w2 staging
  __shared__ bhalf bufP[64*72];
  int blk = blockIdx.x;           // bt*5 + u
  int bt = blk / 5;
  int tid = threadIdx.x, w = tid >> 6, l = tid & 63;
  const bhalf* Pt = PT + (size_t)blk*16384;
  // phase 1: q1 (M=64, N=128, K=256) -> bufA bf16
  {
    bf8v a8[8];
    #pragma unroll
    for (int kt = 0; kt < 8; ++kt) a8[kt] = ldfrag(Pt, w*16, kt*32, 256, l);
    #pragma unroll
    for (int nt = 0; nt < 8; ++nt) {
      f4 acc = {0.f,0.f,0.f,0.f};
      #pragma unroll
      for (int kt = 0; kt < 8; ++kt)
        acc = mfma16(a8[kt], ldfrag(WT + W_FAMQ, nt*16, kt*32, 256, l), acc);
      #pragma unroll
      for (int reg = 0; reg < 4; ++reg)
        bufA[(w*16 + ((l>>4)<<2) + reg)*280 + nt*16 + (l&15)] = f2b(acc[reg]);
    }
  }
  __syncthreads();
  // phase 2: scores vs k1 (own-wave rows from bufA), softmax in regs
  float sv[4][4];
  {
    const bhalf* K1 = K1B + (size_t)bt*8192;
    bf8v aq[4];
    #pragma unroll
    for (int kt = 0; kt < 4; ++kt) aq[kt] = ldfrag(bufA, w*16, kt*32, 280, l);
    #pragma unroll
    for (int nt = 0; nt < 4; ++nt) {
      f4 acc = {0.f,0.f,0.f,0.f};
      #pragma unroll
      for (int kt = 0; kt < 4; ++kt)
        acc = mfma16(aq[kt], ldfrag(K1, nt*16, kt*32, 128, l), acc);
      #pragma unroll
      for (int reg = 0; reg < 4; ++reg) sv[nt][reg] = acc[reg] * ATT_SCALE;
    }
  }
  if ((l & 15) > 0) { sv[3][0] = -1e30f; sv[3][1] = -1e30f; sv[3][2] = -1e30f; sv[3][3] = -1e30f; }
  regSoftmax(sv);
  #pragma unroll
  for (int nt = 0; nt < 4; ++nt)
    #pragma unroll
    for (int reg = 0; reg < 4; ++reg)
      bufP[(w*16 + ((l>>4)<<2) + reg)*72 + nt*16 + (l&15)] = f2b(sv[nt][reg]);
  __syncthreads();
  // phase 3: PVs
  bf8v ap0 = ldfrag(bufP, w*16, 0, 72, l);
  bf8v ap1 = ldfrag(bufP, w*16, 32, 72, l);
  {
    const bhalf* vq = VQT + (size_t)bt*8192;
    bhalf* q2 = Q2B + (size_t)blk*8192;
    #pragma unroll
    for (int nt = 0; nt < 8; ++nt) {
      f4 acc = {0.f,0.f,0.f,0.f};
      acc = mfma16(ap0, ldfrag(vq, nt*16, 0, 64, l), acc);
      acc = mfma16(ap1, ldfrag(vq, nt*16, 32, 64, l), acc);
      #pragma unroll
      for (int reg = 0; reg < 4; ++reg) {
        int p = w*16 + ((l>>4)<<2) + reg;
        q2[(size_t)p*128 + nt*16 + (l&15)] = (p < 49) ? f2b(acc[reg]) : (bhalf)0;
      }
    }
  }
  {
    const bhalf* vk = VKT + (size_t)bt*8192;
    bhalf* k2 = K2B + (size_t)blk*8192;
    #pragma unroll
    for (int nt = 0; nt < 8; ++nt) {
      f4 acc = {0.f,0.f,0.f,0.f};
      acc = mfma16(ap0, ldfrag(vk, nt*16, 0, 64, l), acc);
      acc = mfma16(ap1, ldfrag(vk, nt*16, 32, 64, l), acc);
      #pragma unroll
      for (int reg = 0; reg < 4; ++reg) {
        int p = w*16 + ((l>>4)<<2) + reg;
        k2[(size_t)p*128 + nt*16 + (l&15)] = (p < 49) ? f2b(acc[reg]) : (bhalf)0;
      }
    }
  }
  {
    const bhalf* vw = VWT + (size_t)bt*16384;
    #pragma unroll
    for (int nt = 0; nt < 16; ++nt) {
      f4 acc = {0.f,0.f,0.f,0.f};
      acc = mfma16(ap0, ldfrag(vw, nt*16, 0, 64, l), acc);
      acc = mfma16(ap1, ldfrag(vw, nt*16, 32, 64, l), acc);
      #pragma unroll
      for (int reg = 0; reg < 4; ++reg)
        bufA[(w*16 + ((l>>4)<<2) + reg)*280 + nt*16 + (l&15)] = f2b(acc[reg]);
    }
  }
  __syncthreads();
  // epilogue: w2t[c][r] coalesced (pairs packed into u32)
  unsigned* wt = reinterpret_cast<unsigned*>(W2T + (size_t)blk*16384);
  for (int it = 0; it < 32; ++it) {
    int o = it*256 + tid;       // 0..8191
    int c = o >> 5, ii = o & 31;
    int r0 = ii*2;
    unsigned lo = (r0   < 49) ? (unsigned)bufA[r0*280 + c]     : 0u;
    unsigned hi = (r0+1 < 49) ? (unsigned)bufA[(r0+1)*280 + c] : 0u;
    wt[o] = lo | (hi << 16);
  }
}

// ---------- stage 2: ARM attention + edge stats ----------
// One block per (bt,i). K_i/V_i staged once in LDS (XOR-swizzled). The j-loop is
// BARRIER-FREE: bufP is wave-private (wave w writes+reads rows w*16..w*16+15),
// cross-wave hw-sums deferred into redH[w][j][c] (per-wave slices), sqa in regs.
// Single barrier + epilogue does cross-wave sums, hws stores, BN-stat atomics.
__global__ void __launch_bounds__(256) s2ker(const bhalf* Q2B, const bhalf* K2B, const bhalf* W2T,
    const float* epb, float* hws, float* gs1, float* gs2)
{
  __shared__ bhalf Kl[64*128];        // 16 KB, swizzled rows of 256 B
  __shared__ bhalf Vl[256*64];        // 32 KB, swizzled rows of 128 B
  __shared__ bhalf bufP[64*72];       // 9 KB, wave-private
  __shared__ float redH[4][5][256];   // 20 KB, per-wave per-j column partials
  __shared__ float redS2[5][4][2];    // final reduction staging
  int orig = blockIdx.x;
  int blk = (orig & 7) * 80 + (orig >> 3);   // 640 = 8*80, bijective XCD grouping
  int i = blk % 5, bt = blk / 5, b = bt >> 4, t = bt & 15;
  int tid = threadIdx.x, w = tid >> 6, l = tid & 63;
  const bhalf* K = K2B + (size_t)(bt*5 + i)*8192;
  const bhalf* V = W2T + (size_t)(bt*5 + i)*16384;
  // prefetch j=0 Q fragments before staging (independent of LDS)
  bf8v aq[4];
  {
    const bhalf* Q0 = Q2B + (size_t)(bt*5 + 0)*8192;
    #pragma unroll
    for (int kt = 0; kt < 4; ++kt) aq[kt] = ldfrag(Q0, w*16, kt*32, 128, l);
  }
  // ---- stage K (16 KB) and V (32 KB): coalesced global read, swizzled LDS write ----
  {
    const char* gk = reinterpret_cast<const char*>(K);
    const char* gv = reinterpret_cast<const char*>(V);
    char* lk = reinterpret_cast<char*>(Kl);
    char* lv = reinterpret_cast<char*>(Vl);
    #pragma unroll
    for (int c = 0; c < 4; ++c) {
      int x = (c*256 + tid) << 4;                 // K: row = x>>8 (256 B rows)
      float4 val = *reinterpret_cast<const float4*>(gk + x);
      *reinterpret_cast<float4*>(lk + (x ^ (((x >> 8) & 7) << 4))) = val;
    }
    #pragma unroll
    for (int c = 0; c < 8; ++c) {
      int x = (c*256 + tid) << 4;                 // V: row = x>>7 (128 B rows)
      float4 val = *reinterpret_cast<const float4*>(gv + x);
      *reinterpret_cast<float4*>(lv + (x ^ (((x >> 7) & 7) << 4))) = val;
    }
  }
  __syncthreads();

  float sqa[5];
  #pragma unroll
  for (int j = 0; j < 5; ++j) {
    // prefetch next j's Q fragments (hides global latency under this j's compute)
    bf8v aqn[4];
    if (j < 4) {
      const bhalf* Qn = Q2B + (size_t)(bt*5 + j + 1)*8192;
      #pragma unroll
      for (int kt = 0; kt < 4; ++kt) aqn[kt] = ldfrag(Qn, w*16, kt*32, 128, l);
    }
    float sv[4][4];
    #pragma unroll
    for (int nt = 0; nt < 4; ++nt) {
      f4 acc = {0.f,0.f,0.f,0.f};
      #pragma unroll
      for (int kt = 0; kt < 4; ++kt)
        acc = mfma16(aq[kt], ldswz(Kl, nt*16 + (l & 15), kt*64 + ((l >> 4) << 4), 256), acc);
      #pragma unroll
      for (int reg = 0; reg < 4; ++reg) sv[nt][reg] = acc[reg] * ATT_SCALE;
    }
    if ((l & 15) > 0) { sv[3][0] = -1e30f; sv[3][1] = -1e30f; sv[3][2] = -1e30f; sv[3][3] = -1e30f; }
    regSoftmax(sv);
    // wave-private P transpose through LDS (no barrier needed)
    #pragma unroll
    for (int nt = 0; nt < 4; ++nt)
      #pragma unroll
      for (int reg = 0; reg < 4; ++reg)
        bufP[(w*16 + ((l>>4)<<2) + reg)*72 + nt*16 + (l&15)] = f2b(sv[nt][reg]);
    bf8v ap0 = ldfrag(bufP, w*16, 0, 72, l);
    bf8v ap1 = ldfrag(bufP, w*16, 32, 72, l);
    float sq = 0.f;
    #pragma unroll
    for (int nt2 = 0; nt2 < 16; ++nt2) {
      f4 acc = {0.f,0.f,0.f,0.f};
      acc = mfma16(ap0, ldswz(Vl, nt2*16 + (l & 15), ((l >> 4) << 4), 128), acc);
      acc = mfma16(ap1, ldswz(Vl, nt2*16 + (l & 15), 64 + ((l >> 4) << 4), 128), acc);
      int c = nt2*16 + (l & 15);
      float bias = epb[c];
      float hw = 0.f;
      #pragma unroll
      for (int reg = 0; reg < 4; ++reg) {
        int p = w*16 + ((l>>4)<<2) + reg;
        if (p < 49) { float v = acc[reg] + bias; hw += v; sq += v*v; }
      }
      hw += __shfl_xor(hw, 16);
      hw += __shfl_xor(hw, 32);
      if ((l >> 4) == 0) redH[w][j][c] = hw;   // wave-private slice
    }
    sqa[j] = sq;
    #pragma unroll
    for (int kt = 0; kt < 4; ++kt) aq[kt] = (j < 4) ? aqn[kt] : aq[kt];
  }
  __syncthreads();   // the ONLY barrier after staging
  // epilogue: cross-wave column sums, hws stores, BN stats
  float g1[5];
  #pragma unroll
  for (int j = 0; j < 5; ++j) {
    float hwtot = redH[0][j][tid] + redH[1][j][tid] + redH[2][j][tid] + redH[3][j][tid];
    hws[(((size_t)(b*25 + i*5 + j)*16) + t)*256 + tid] = hwtot;
    g1[j] = hwtot;
  }
  #pragma unroll
  for (int j = 0; j < 5; ++j) {
    float a = g1[j], s = sqa[j];
    #pragma unroll
    for (int off = 32; off; off >>= 1) { a += __shfl_down(a, off); s += __shfl_down(s, off); }
    if (l == 0) { redS2[j][w][0] = a; redS2[j][w][1] = s; }
  }
  __syncthreads();
  if (tid < 5) {
    int j = tid;
    atomicAdd(gs1 + i*5 + j, redS2[j][0][0]+redS2[j][1][0]+redS2[j][2][0]+redS2[j][3][0]);
    atomicAdd(gs2 + i*5 + j, redS2[j][0][1]+redS2[j][1][1]+redS2[j][2][1]+redS2[j][3][1]);
  }
}

// f_e = gem-BN applied to hw-mean
__global__ void __launch_bounds__(256) s2finker(const float* hws, const float* gs1, const float* gs2,
                                                const float* gg, const float* gb, float* EDG) {
  int blk = blockIdx.x;
  int e = (blk >> 4) % 25;
  size_t idx = (size_t)blk*256 + threadIdx.x;
  constexpr float invCnt = 1.f/1605632.f;
  float m = gs1[e]*invCnt;
  float var = gs2[e]*invCnt - m*m;
  float rstd = rsqrtf(var + 1e-5f);
  EDG[idx] = gg[e]*((hws[idx]*(1.f/49.f) - m)*rstd) + gb[e];
}

// ---------- GNN kernels (f32, unchanged) ----------

__global__ void __launch_bounds__(256) gnnProj(const float* X, const float* EDG,
    const float* Wa, const float* Wb, const float* Wu, const float* Wv, const float* We,
    float* xA, float* xB, float* xU, float* xV, float* eE) {
  int blk = blockIdx.x, tid = threadIdx.x;
  const float* src; const float* W; float* dst; int r0;
  if (blk < 160) {
    int m = blk / 40; r0 = (blk % 40) * 16;
    src = X;
    W   = (m==0)?Wa:(m==1)?Wb:(m==2)?Wu:Wv;
    dst = (m==0)?xA:(m==1)?xB:(m==2)?xU:xV;
  } else { r0 = (blk-160)*16; src = EDG; W = We; dst = eE; }
  float acc[16];
  #pragma unroll
  for (int r = 0; r < 16; ++r) acc[r] = 0.f;
  for (int c = 0; c < 256; c += 4) {
    float w0 = W[(size_t)(c+0)*256 + tid];
    float w1 = W[(size_t)(c+1)*256 + tid];
    float w2 = W[(size_t)(c+2)*256 + tid];
    float w3 = W[(size_t)(c+3)*256 + tid];
    #pragma unroll
    for (int r = 0; r < 16; ++r) {
      float4 a = *reinterpret_cast<const float4*>(&src[(size_t)(r0+r)*256 + c]);
      acc[r] += a.x*w0 + a.y*w1 + a.z*w2 + a.w*w3;
    }
  }
  #pragma unroll
  for (int r = 0; r < 16; ++r) dst[(size_t)(r0+r)*256 + tid] = acc[r];
}

__global__ void __launch_bounds__(256) g2a(const float* xA, const float* xB, const float* eE,
                                           float* ET, float* s1, float* s2) {
  __shared__ float red[8];
  int blk = blockIdx.x, tid = threadIdx.x;
  int b = blk / 400, e = (blk >> 4) % 25, t = blk & 15;
  int i = e / 5, j = e % 5;
  size_t ni = ((size_t)(b*5+i)*16 + t)*256 + tid;
  size_t nj = ((size_t)(b*5+j)*16 + t)*256 + tid;
  size_t ee = (size_t)blk*256 + tid;
  float v = xA[ni] + xB[nj] + eE[ee];
  ET[ee] = v;
  reduce2Atomic(v, v*v, s1 + e, s2 + e, red);
}

__global__ void __launch_bounds__(256) g2b(const float* ET, float* EDG, const float* g, const float* bb,
                                           const float* s1, const float* s2) {
  int blk = blockIdx.x, tid = threadIdx.x;
  int e = (blk >> 4) % 25;
  size_t ee = (size_t)blk*256 + tid;
  constexpr float invCnt = 1.f/32768.f;
  float m = s1[e]*invCnt;
  float var = s2[e]*invCnt - m*m;
  float rstd = rsqrtf(var + 1e-5f);
  float v = g[e]*((ET[ee]-m)*rstd) + bb[e];
  if (v != v) v = 0.f;
  EDG[ee] += fmaxf(v, 0.f);
}

__global__ void __launch_bounds__(256) g3a(const float* EDG, const float* xV, const float* xU,
                                           float* XN, float* s1, float* s2) {
  __shared__ float red[8];
  int blk = blockIdx.x, tid = threadIdx.x;
  int b = blk / 80, i = (blk >> 4) % 5, t = blk & 15;
  float ex[5]; float ssum = 0.f;
  #pragma unroll
  for (int j = 0; j < 5; ++j) {
    float ev = EDG[((size_t)(b*25 + i*5 + j)*16 + t)*256 + tid];
    float sg = 1.f/(1.f + __expf(-ev));
    ex[j] = __expf(sg);
    ssum += ex[j];
  }
  float inv = 1.f/ssum;
  float agg = 0.f;
  #pragma unroll
  for (int j = 0; j < 5; ++j)
    agg += ex[j]*inv * xV[((size_t)(b*5+j)*16 + t)*256 + tid];
  agg *= 0.2f;
  size_t ni = (size_t)blk*256 + tid;
  float xn = xU[ni] + agg;
  XN[ni] = xn;
  reduce2Atomic(xn, xn*xn, s1 + i, s2 + i, red);
}

__global__ void __launch_bounds__(256) g3b(const float* XN, float* X, const float* g, const float* bb,
                                           const float* s1, const float* s2, int mask) {
  int blk = blockIdx.x, tid = threadIdx.x;
  int i = (blk >> 4) % 5;
  size_t ni = (size_t)blk*256 + tid;
  constexpr float invCnt = 1.f/32768.f;
  float m = s1[i]*invCnt;
  float var = s2[i]*invCnt - m*m;
  float rstd = rsqrtf(var + 1e-5f);
  float v = g[i]*((XN[ni]-m)*rstd) + bb[i];
  if (mask && v != v) v = 0.f;
  X[ni] = fmaxf(X[ni] + v, 0.f);
}

__global__ void __launch_bounds__(256) finker(const float* X, const float* EDG,
                                              const float* sc, const float* efw, const float* efb,
                                              float* out) {
  __shared__ float red[12];
  int blk = blockIdx.x, tid = threadIdx.x;
  if (blk < 640) {
    int nn = (blk >> 4) % 5;
    float x = X[(size_t)blk*256 + tid];
    float s = fmaxf(sc[nn*256 + tid], 0.f);
    float xx = x*x, ss = s*s, xs = x*s;
    #pragma unroll
    for (int off = 32; off; off >>= 1) {
      xx += __shfl_down(xx, off); ss += __shfl_down(ss, off); xs += __shfl_down(xs, off);
    }
    if ((tid & 63) == 0) { int w = tid >> 6; red[w*3] = xx; red[w*3+1] = ss; red[w*3+2] = xs; }
    __syncthreads();
    if (tid == 0) {
      float sxx = red[0]+red[3]+red[6]+red[9];
      float sss = red[1]+red[4]+red[7]+red[10];
      float sxs = red[2]+red[5]+red[8]+red[11];
      float nx = fmaxf(sqrtf(sxx), 1e-12f);
      float ns = fmaxf(sqrtf(sss), 1e-12f);
      out[blk] = sxs / (nx * ns);
    }
  } else {
    int eb = blk - 640;
    float v = EDG[(size_t)eb*256 + tid] * efw[tid];
    #pragma unroll
    for (int off = 32; off; off >>= 1) v += __shfl_down(v, off);
    if ((tid & 63) == 0) red[tid >> 6] = v;
    __syncthreads();
    if (tid == 0) out[640 + eb] = red[0]+red[1]+red[2]+red[3] + efb[0];
  }
}

// ---------- host ----------

extern "C" void kernel_launch(void* const* d_in, const int* in_sizes, int n_in,
                              void* d_out, int out_size, void* d_ws, size_t ws_size,
                              hipStream_t stream) {
  (void)in_sizes; (void)n_in; (void)out_size; (void)ws_size;
  const float* af    = (const float*)d_in[0];
  const float* ef    = (const float*)d_in[1];
  const float* gfm   = (const float*)d_in[2];
  const float* attf  = (const float*)d_in[3];
  const float* sfm   = (const float*)d_in[4];
  const float* fam_q = (const float*)d_in[5];
  const float* fam_k = (const float*)d_in[6];
  const float* fam_v = (const float*)d_in[7];
  const float* arm_q = (const float*)d_in[8];
  const float* arm_k = (const float*)d_in[9];
  const float* arm_v = (const float*)d_in[10];
  const float* epw   = (const float*)d_in[11];
  const float* epb   = (const float*)d_in[12];
  const float* gemg  = (const float*)d_in[13];
  const float* gemb  = (const float*)d_in[14];
  const float* Us[2]   = {(const float*)d_in[15], (const float*)d_in[20]};
  const float* Vs[2]   = {(const float*)d_in[16], (const float*)d_in[21]};
  const float* As[2]   = {(const float*)d_in[17], (const float*)d_in[22]};
  const float* Bs[2]   = {(const float*)d_in[18], (const float*)d_in[23]};
  const float* Es[2]   = {(const float*)d_in[19], (const float*)d_in[24]};
  const float* bnvg[2] = {(const float*)d_in[25], (const float*)d_in[29]};
  const float* bnvb[2] = {(const float*)d_in[26], (const float*)d_in[30]};
  const float* bneg[2] = {(const float*)d_in[27], (const float*)d_in[31]};
  const float* bneb[2] = {(const float*)d_in[28], (const float*)d_in[32]};
  const float* scp  = (const float*)d_in[33];
  const float* efw  = (const float*)d_in[34];
  const float* efb  = (const float*)d_in[35];

  char* ws = (char*)d_ws;
  bhalf* PT  = (bhalf*)(ws + O_PT);
  bhalf* WTS = (bhalf*)(ws + O_WTS);
  bhalf* K1B = (bhalf*)(ws + O_K1B);
  bhalf* V1B = (bhalf*)(ws + O_V1B);
  bhalf* VQT = (bhalf*)(ws + O_VQT);
  bhalf* VKT = (bhalf*)(ws + O_VKT);
  bhalf* VTB = (bhalf*)(ws + O_VTB);
  bhalf* VWT = (bhalf*)(ws + O_VWT);
  bhalf* Q2B = (bhalf*)(ws + O_Q2B);
  bhalf* K2B = (bhalf*)(ws + O_K2B);
  bhalf* W2T = (bhalf*)(ws + O_W2T);
  float* FV  = (float*)(ws + O_FV);
  float* HWS = (float*)(ws + O_HWS);
  float* EDG = (float*)(ws + O_EDG);
  float* st  = (float*)(ws + O_ST);
  float* XA  = (float*)(ws + O_XA);
  float* XB  = (float*)(ws + O_XB);
  float* XU  = (float*)(ws + O_XU);
  float* XV  = (float*)(ws + O_XV);
  float* EE  = (float*)(ws + O_EE);
  float* ET  = (float*)(ws + O_ET);
  float* XN  = (float*)(ws + O_XN);

  hipMemsetAsync(st, 0, 256*sizeof(float), stream);

  wprep<<<1280, TPB, 0, stream>>>(fam_q, fam_k, fam_v, arm_q, arm_k, arm_v, epw, WTS);
  modprep<<<640, TPB, 0, stream>>>(af, ef, gfm, attf, sfm, PT, FV);
  kv1a<<<dim3(128, 3), TPB, 0, stream>>>(PT, WTS, K1B, V1B);
  kv1b<<<dim3(128, 3), TPB, 0, stream>>>(V1B, WTS, VQT, VKT, VTB);
  kv1c<<<dim3(128, 2), TPB, 0, stream>>>(VTB, WTS, VWT);
  s1ker<<<640, TPB, 0, stream>>>(PT, WTS, K1B, VQT, VKT, VWT, Q2B, K2B, W2T);
  s2ker<<<640, TPB, 0, stream>>>(Q2B, K2B, W2T, epb, HWS, st+0, st+25);
  s2finker<<<3200, TPB, 0, stream>>>(HWS, st+0, st+25, gemg, gemb, EDG);

  for (int L = 0; L < 2; ++L) {
    float* es1 = st + 64 + L*64;
    float* es2 = es1 + 25;
    float* ns1 = es1 + 50;
    float* ns2 = es1 + 55;
    gnnProj<<<360, TPB, 0, stream>>>(FV, EDG, As[L], Bs[L], Us[L], Vs[L], Es[L],
                                     XA, XB, XU, XV, EE);
    g2a<<<3200, TPB, 0, stream>>>(XA, XB, EE, ET, es1, es2);
    g2b<<<3200, TPB, 0, stream>>>(ET, EDG, bneg[L], bneb[L], es1, es2);
    g3a<<<640, TPB, 0, stream>>>(EDG, XV, XU, XN, ns1, ns2);
    g3b<<<640, TPB, 0, stream>>>(XN, FV, bnvg[L], bnvb[L], ns1, ns2, L == 0 ? 1 : 0);
  }

  finker<<<3840, TPB, 0, stream>>>(FV, EDG, scp, efw, efb, (float*)d_out);
}

// Round 3
// 446.366 us; speedup vs baseline: 1.2108x; 1.0724x over previous
//
#include <hip/hip_runtime.h>

#define DEV __device__ __forceinline__

typedef unsigned short bhalf;
typedef __attribute__((ext_vector_type(8))) short bf8v;
typedef __attribute__((ext_vector_type(4))) float f4;

namespace {
constexpr int TPB = 256;
constexpr float ATT_SCALE = 0.08838834764831845f; // 1/sqrt(128)

// ---- workspace byte offsets ----
constexpr size_t O_PT  = 0;          // bf16 [640][64][256]  modalities, zero-pad rows
constexpr size_t O_WTS = 20971520;   // bf16 transposed weights (see W_* below)
constexpr size_t O_K1B = 21626880;   // bf16 [128][64][128]
constexpr size_t O_V1B = 23724032;   // bf16 [128][64][256]
constexpr size_t O_VQT = 27918336;   // bf16 [128][128][64]  (v1@arm_q)^T
constexpr size_t O_VKT = 30015488;   // bf16 [128][128][64]
constexpr size_t O_VTB = 32112640;   // bf16 [128][64][256]  v1@arm_v
constexpr size_t O_VWT = 36306944;   // bf16 [128][256][64]  (vt@epw)^T
constexpr size_t O_Q2B = 40501248;   // bf16 [640][64][128]
constexpr size_t O_K2B = 50987008;   // bf16 [640][64][128]
constexpr size_t O_W2T = 61472768;   // bf16 [640][256][64]
constexpr size_t O_FV  = 82444288;   // f32  [640][256]  node features X
constexpr size_t O_HWS = 83099648;   // f32  [3200][256]
constexpr size_t O_EDG = 86376448;   // f32  [3200][256]
constexpr size_t O_ST  = 89653248;   // f32  [256] stats
constexpr size_t O_XA  = 89654272;
constexpr size_t O_XB  = 90309632;
constexpr size_t O_XU  = 90964992;
constexpr size_t O_XV  = 91620352;
constexpr size_t O_EE  = 92275712;
constexpr size_t O_ET  = 95552512;
constexpr size_t O_XN  = 98829312;

// WTS element offsets (bf16 elems), all stored as Wt[n][k=256]
constexpr size_t W_FAMQ = 0, W_FAMK = 32768, W_ARMQ = 65536, W_ARMK = 98304,
                 W_FAMV = 131072, W_ARMV = 196608, W_EPW = 262144;
} // namespace

// ---------- helpers ----------

DEV bhalf f2b(float f) {
  unsigned u = __float_as_uint(f);
  return (bhalf)((u + 0x7FFFu + ((u >> 16) & 1u)) >> 16);
}

DEV f4 mfma16(bf8v a, bf8v b, f4 c) {
  return __builtin_amdgcn_mfma_f32_16x16x32_bf16(a, b, c, 0, 0, 0);
}

// fragment load: lane l reads row (r0 + (l&15)), 8 contiguous k at k0 + (l>>4)*8
DEV bf8v ldfrag(const bhalf* base, int r0, int k0, int S, int l) {
  return *reinterpret_cast<const bf8v*>(base + (size_t)(r0 + (l & 15)) * S + k0 + ((l >> 4) << 3));
}

// swizzled LDS fragment load: byte = row*stride + koffB, XOR'd with ((row&7)<<4)
DEV bf8v ldswz(const bhalf* base, int row, int koffB, int strideB) {
  int byte = row * strideB + koffB;
  byte ^= ((row & 7) << 4);
  return *reinterpret_cast<const bf8v*>(reinterpret_cast<const char*>(base) + byte);
}

// in-register row softmax: sv[nt][reg], row per reg spans cols nt*16+(l&15) across 16 lanes
DEV void regSoftmax(float sv[4][4]) {
  #pragma unroll
  for (int reg = 0; reg < 4; ++reg) {
    float m = fmaxf(fmaxf(sv[0][reg], sv[1][reg]), fmaxf(sv[2][reg], sv[3][reg]));
    #pragma unroll
    for (int off = 1; off <= 8; off <<= 1) m = fmaxf(m, __shfl_xor(m, off));
    float s = 0.f;
    #pragma unroll
    for (int nt = 0; nt < 4; ++nt) { float e = __expf(sv[nt][reg] - m); sv[nt][reg] = e; s += e; }
    #pragma unroll
    for (int off = 1; off <= 8; off <<= 1) s += __shfl_xor(s, off);
    float inv = 1.f / s;
    #pragma unroll
    for (int nt = 0; nt < 4; ++nt) sv[nt][reg] *= inv;
  }
}

DEV void reduce2Atomic(float a, float b, float* ga, float* gb, float* red) {
  #pragma unroll
  for (int off = 32; off; off >>= 1) { a += __shfl_down(a, off); b += __shfl_down(b, off); }
  if ((threadIdx.x & 63) == 0) { int w = threadIdx.x >> 6; red[w*2] = a; red[w*2+1] = b; }
  __syncthreads();
  if (threadIdx.x == 0) {
    atomicAdd(ga, red[0]+red[2]+red[4]+red[6]);
    atomicAdd(gb, red[1]+red[3]+red[5]+red[7]);
  }
}

// ---------- prep kernels ----------

// transpose 7 weight matrices to bf16 Wt[n][256]
__global__ void __launch_bounds__(256) wprep(const float* fq, const float* fk, const float* fv,
                                             const float* aq, const float* ak, const float* av,
                                             const float* ep, bhalf* WT) {
  int blk = blockIdx.x, tid = threadIdx.x;
  const float* src; bhalf* dst; int N, n;
  if (blk < 512) {
    int m = blk >> 7; n = blk & 127; N = 128;
    src = (m==0)?fq:(m==1)?fk:(m==2)?aq:ak;
    dst = WT + (size_t)m*32768;
  } else {
    int r = blk - 512; int m = r >> 8; n = r & 255; N = 256;
    src = (m==0)?fv:(m==1)?av:ep;
    dst = WT + 131072 + (size_t)m*65536;
  }
  dst[(size_t)n*256 + tid] = f2b(src[(size_t)tid*N + n]);
}

// per (bt,u): transpose modality slice to bf16 Pt[64][256] (zero-pad rows) + fv means
__global__ void __launch_bounds__(256) modprep(const float* af, const float* ef, const float* gf,
                                               const float* attf, const float* sf,
                                               bhalf* PT, float* FV) {
  __shared__ float lb[49*260];
  int blk = blockIdx.x, tid = threadIdx.x;
  int u = blk % 5, bt = blk / 5, b = bt >> 4, t = bt & 15;
  const float* src = (u==0)?af:(u==1)?ef:(u==2)?gf:(u==3)?attf:sf;
  src += ((size_t)b*256*16 + t)*49;
  for (int o = tid; o < 49*256; o += TPB) {
    int c = o / 49, p = o % 49;
    lb[p*260 + c] = src[(size_t)c*784 + p];
  }
  __syncthreads();
  bhalf* pt = PT + (size_t)blk*16384;
  for (int p = 0; p < 64; ++p)
    pt[p*256 + tid] = (p < 49) ? f2b(lb[p*260 + tid]) : (bhalf)0;
  float s = 0.f;
  for (int p = 0; p < 49; ++p) s += lb[p*260 + tid];
  FV[(((size_t)(b*5+u)*16) + t)*256 + tid] = s * (1.f/49.f);
}

// ---------- MFMA GEMM chain (nt-split over blockIdx.y for parallelism) ----------

// per (bt, part): part0: k1 = Paf@fam_k [64][128]; part1/2: v1 = Paf@fam_v halves
__global__ void __launch_bounds__(256) kv1a(const bhalf* PT, const bhalf* WT,
                                            bhalf* K1B, bhalf* V1B) {
  int bt = blockIdx.x, part = blockIdx.y;
  int tid = threadIdx.x, w = tid >> 6, l = tid & 63;
  const bhalf* A = PT + (size_t)bt*5*16384; // u=0 (af)
  bf8v a8[8];
  #pragma unroll
  for (int kt = 0; kt < 8; ++kt) a8[kt] = ldfrag(A, w*16, kt*32, 256, l);
  if (part == 0) {
    bhalf* o1 = K1B + (size_t)bt*8192;
    #pragma unroll
    for (int nt = 0; nt < 8; ++nt) {
      f4 acc = {0.f,0.f,0.f,0.f};
      #pragma unroll
      for (int kt = 0; kt < 8; ++kt)
        acc = mfma16(a8[kt], ldfrag(WT + W_FAMK, nt*16, kt*32, 256, l), acc);
      #pragma unroll
      for (int reg = 0; reg < 4; ++reg) {
        int p = w*16 + ((l>>4)<<2) + reg;
        o1[(size_t)p*128 + nt*16 + (l&15)] = f2b(acc[reg]);
      }
    }
  } else {
    bhalf* o2 = V1B + (size_t)bt*16384;
    int nt0 = (part - 1) * 8;
    #pragma unroll
    for (int nn = 0; nn < 8; ++nn) {
      int nt = nt0 + nn;
      f4 acc = {0.f,0.f,0.f,0.f};
      #pragma unroll
      for (int kt = 0; kt < 8; ++kt)
        acc = mfma16(a8[kt], ldfrag(WT + W_FAMV, nt*16, kt*32, 256, l), acc);
      #pragma unroll
      for (int reg = 0; reg < 4; ++reg) {
        int p = w*16 + ((l>>4)<<2) + reg;
        o2[(size_t)p*256 + nt*16 + (l&15)] = f2b(acc[reg]);
      }
    }
  }
}

// per (bt, part): part0: vqt/vkt transposed [128][64]; part1/2: vtb = v1@arm_v halves
__global__ void __launch_bounds__(256) kv1b(const bhalf* V1B, const bhalf* WT,
                                            bhalf* VQT, bhalf* VKT, bhalf* VTB) {
  int bt = blockIdx.x, part = blockIdx.y;
  int tid = threadIdx.x, w = tid >> 6, l = tid & 63;
  const bhalf* A = V1B + (size_t)bt*16384;
  bf8v a8[8];
  #pragma unroll
  for (int kt = 0; kt < 8; ++kt) a8[kt] = ldfrag(A, w*16, kt*32, 256, l);
  if (part == 0) {
    bhalf* oq = VQT + (size_t)bt*8192;
    bhalf* ok = VKT + (size_t)bt*8192;
    #pragma unroll
    for (int nt = 0; nt < 8; ++nt) {
      f4 accq = {0.f,0.f,0.f,0.f}, acck = {0.f,0.f,0.f,0.f};
      #pragma unroll
      for (int kt = 0; kt < 8; ++kt) {
        accq = mfma16(a8[kt], ldfrag(WT + W_ARMQ, nt*16, kt*32, 256, l), accq);
        acck = mfma16(a8[kt], ldfrag(WT + W_ARMK, nt*16, kt*32, 256, l), acck);
      }
      #pragma unroll
      for (int reg = 0; reg < 4; ++reg) {
        int p = w*16 + ((l>>4)<<2) + reg;
        int n = nt*16 + (l&15);
        oq[(size_t)n*64 + p] = f2b(accq[reg]);   // transposed store
        ok[(size_t)n*64 + p] = f2b(acck[reg]);
      }
    }
  } else {
    bhalf* ov = VTB + (size_t)bt*16384;
    int nt0 = (part - 1) * 8;
    #pragma unroll
    for (int nn = 0; nn < 8; ++nn) {
      int nt = nt0 + nn;
      f4 acc = {0.f,0.f,0.f,0.f};
      #pragma unroll
      for (int kt = 0; kt < 8; ++kt)
        acc = mfma16(a8[kt], ldfrag(WT + W_ARMV, nt*16, kt*32, 256, l), acc);
      #pragma unroll
      for (int reg = 0; reg < 4; ++reg) {
        int p = w*16 + ((l>>4)<<2) + reg;
        ov[(size_t)p*256 + nt*16 + (l&15)] = f2b(acc[reg]);
      }
    }
  }
}

// per (bt, part): vwt = (vt@epw)^T [256][64], nt halves
__global__ void __launch_bounds__(256) kv1c(const bhalf* VTB, const bhalf* WT, bhalf* VWT) {
  int bt = blockIdx.x, part = blockIdx.y;
  int tid = threadIdx.x, w = tid >> 6, l = tid & 63;
  const bhalf* A = VTB + (size_t)bt*16384;
  bf8v a8[8];
  #pragma unroll
  for (int kt = 0; kt < 8; ++kt) a8[kt] = ldfrag(A, w*16, kt*32, 256, l);
  bhalf* ow = VWT + (size_t)bt*16384;
  int nt0 = part * 8;
  #pragma unroll
  for (int nn = 0; nn < 8; ++nn) {
    int nt = nt0 + nn;
    f4 acc = {0.f,0.f,0.f,0.f};
    #pragma unroll
    for (int kt = 0; kt < 8; ++kt)
      acc = mfma16(a8[kt], ldfrag(WT + W_EPW, nt*16, kt*32, 256, l), acc);
    #pragma unroll
    for (int reg = 0; reg < 4; ++reg) {
      int p = w*16 + ((l>>4)<<2) + reg;
      ow[(size_t)(nt*16 + (l&15))*64 + p] = f2b(acc[reg]);  // transposed
    }
  }
}

// ---------- stage 1: FAM attention + ARM input projections ----------
// per (bt,u): q1 = Pt@fam_q; P = softmax(q1 k1^T * s); q2 = P@vq, k2 = P@vk, w2t = (P@vw)^T
__global__ void __launch_bounds__(256) s1ker(const bhalf* PT, const bhalf* WT,
    const bhalf* K1B, const bhalf* VQT, const bhalf* VKT, const bhalf* VWT,
    bhalf* Q2B, bhalf* K2B, bhalf* W2T)
{
  __shared__ bhalf bufA[64*280];  // q1 staging, then w2 staging
  __shared__ bhalf bufP[64*72];
  int blk = blockIdx.x;           // bt*5 + u
  int bt = blk / 5;
  int tid = threadIdx.x, w = tid >> 6, l = tid & 63;
  const bhalf* Pt = PT + (size_t)blk*16384;
  // phase 1: q1 (M=64, N=128, K=256) -> bufA bf16
  {
    bf8v a8[8];
    #pragma unroll
    for (int kt = 0; kt < 8; ++kt) a8[kt] = ldfrag(Pt, w*16, kt*32, 256, l);
    #pragma unroll
    for (int nt = 0; nt < 8; ++nt) {
      f4 acc = {0.f,0.f,0.f,0.f};
      #pragma unroll
      for (int kt = 0; kt < 8; ++kt)
        acc = mfma16(a8[kt], ldfrag(WT + W_FAMQ, nt*16, kt*32, 256, l), acc);
      #pragma unroll
      for (int reg = 0; reg < 4; ++reg)
        bufA[(w*16 + ((l>>4)<<2) + reg)*280 + nt*16 + (l&15)] = f2b(acc[reg]);
    }
  }
  __syncthreads();
  // phase 2: scores vs k1 (own-wave rows from bufA), softmax in regs
  float sv[4][4];
  {
    const bhalf* K1 = K1B + (size_t)bt*8192;
    bf8v aq[4];
    #pragma unroll
    for (int kt = 0; kt < 4; ++kt) aq[kt] = ldfrag(bufA, w*16, kt*32, 280, l);
    #pragma unroll
    for (int nt = 0; nt < 4; ++nt) {
      f4 acc = {0.f,0.f,0.f,0.f};
      #pragma unroll
      for (int kt = 0; kt < 4; ++kt)
        acc = mfma16(aq[kt], ldfrag(K1, nt*16, kt*32, 128, l), acc);
      #pragma unroll
      for (int reg = 0; reg < 4; ++reg) sv[nt][reg] = acc[reg] * ATT_SCALE;
    }
  }
  if ((l & 15) > 0) { sv[3][0] = -1e30f; sv[3][1] = -1e30f; sv[3][2] = -1e30f; sv[3][3] = -1e30f; }
  regSoftmax(sv);
  #pragma unroll
  for (int nt = 0; nt < 4; ++nt)
    #pragma unroll
    for (int reg = 0; reg < 4; ++reg)
      bufP[(w*16 + ((l>>4)<<2) + reg)*72 + nt*16 + (l&15)] = f2b(sv[nt][reg]);
  __syncthreads();
  // phase 3: PVs
  bf8v ap0 = ldfrag(bufP, w*16, 0, 72, l);
  bf8v ap1 = ldfrag(bufP, w*16, 32, 72, l);
  {
    const bhalf* vq = VQT + (size_t)bt*8192;
    bhalf* q2 = Q2B + (size_t)blk*8192;
    #pragma unroll
    for (int nt = 0; nt < 8; ++nt) {
      f4 acc = {0.f,0.f,0.f,0.f};
      acc = mfma16(ap0, ldfrag(vq, nt*16, 0, 64, l), acc);
      acc = mfma16(ap1, ldfrag(vq, nt*16, 32, 64, l), acc);
      #pragma unroll
      for (int reg = 0; reg < 4; ++reg) {
        int p = w*16 + ((l>>4)<<2) + reg;
        q2[(size_t)p*128 + nt*16 + (l&15)] = (p < 49) ? f2b(acc[reg]) : (bhalf)0;
      }
    }
  }
  {
    const bhalf* vk = VKT + (size_t)bt*8192;
    bhalf* k2 = K2B + (size_t)blk*8192;
    #pragma unroll
    for (int nt = 0; nt < 8; ++nt) {
      f4 acc = {0.f,0.f,0.f,0.f};
      acc = mfma16(ap0, ldfrag(vk, nt*16, 0, 64, l), acc);
      acc = mfma16(ap1, ldfrag(vk, nt*16, 32, 64, l), acc);
      #pragma unroll
      for (int reg = 0; reg < 4; ++reg) {
        int p = w*16 + ((l>>4)<<2) + reg;
        k2[(size_t)p*128 + nt*16 + (l&15)] = (p < 49) ? f2b(acc[reg]) : (bhalf)0;
      }
    }
  }
  {
    const bhalf* vw = VWT + (size_t)bt*16384;
    #pragma unroll
    for (int nt = 0; nt < 16; ++nt) {
      f4 acc = {0.f,0.f,0.f,0.f};
      acc = mfma16(ap0, ldfrag(vw, nt*16, 0, 64, l), acc);
      acc = mfma16(ap1, ldfrag(vw, nt*16, 32, 64, l), acc);
      #pragma unroll
      for (int reg = 0; reg < 4; ++reg)
        bufA[(w*16 + ((l>>4)<<2) + reg)*280 + nt*16 + (l&15)] = f2b(acc[reg]);
    }
  }
  __syncthreads();
  // epilogue: w2t[c][r] coalesced (pairs packed into u32)
  unsigned* wt = reinterpret_cast<unsigned*>(W2T + (size_t)blk*16384);
  for (int it = 0; it < 32; ++it) {
    int o = it*256 + tid;       // 0..8191
    int c = o >> 5, ii = o & 31;
    int r0 = ii*2;
    unsigned lo = (r0   < 49) ? (unsigned)bufA[r0*280 + c]     : 0u;
    unsigned hi = (r0+1 < 49) ? (unsigned)bufA[(r0+1)*280 + c] : 0u;
    wt[o] = lo | (hi << 16);
  }
}

// ---------- stage 2: ARM attention + edge stats ----------
// One block per (bt,e) -- maximum TLP (12.5 blocks/CU of work). K_i/V_i staged
// to LDS (XOR-swizzled) with 12 independent float4 loads/thread so all MFMA
// operands come from LDS/registers. Only 2 block-wide barriers. XCD-bijective
// remap puts all 25 e-blocks of one bt on the same XCD (K/V/Q L2 reuse).
__global__ void __launch_bounds__(256) s2ker(const bhalf* Q2B, const bhalf* K2B, const bhalf* W2T,
    const float* epb, float* hws, float* gs1, float* gs2)
{
  __shared__ bhalf Kl[64*128];    // 16 KB, swizzled rows of 256 B
  __shared__ bhalf Vl[256*64];    // 32 KB, swizzled rows of 128 B
  __shared__ bhalf bufP[64*72];   // 9 KB, wave-private
  __shared__ float redH[4*256];   // 4 KB
  __shared__ float redS[8];
  int orig = blockIdx.x;
  int blk = (orig & 7) * 400 + (orig >> 3);   // 3200 = 8*400, bijective XCD grouping
  int e = blk % 25, bt = blk / 25, b = bt >> 4, t = bt & 15;
  int i = e / 5, j = e % 5;
  int tid = threadIdx.x, w = tid >> 6, l = tid & 63;
  const bhalf* K = K2B + (size_t)(bt*5 + i)*8192;
  const bhalf* V = W2T + (size_t)(bt*5 + i)*16384;
  const bhalf* Q = Q2B + (size_t)(bt*5 + j)*8192;
  // prefetch Q fragments (independent of LDS staging)
  bf8v aq[4];
  #pragma unroll
  for (int kt = 0; kt < 4; ++kt) aq[kt] = ldfrag(Q, w*16, kt*32, 128, l);
  // ---- stage K (16 KB) and V (32 KB): coalesced global read, swizzled LDS write ----
  {
    const char* gk = reinterpret_cast<const char*>(K);
    const char* gv = reinterpret_cast<const char*>(V);
    char* lk = reinterpret_cast<char*>(Kl);
    char* lv = reinterpret_cast<char*>(Vl);
    #pragma unroll
    for (int c = 0; c < 4; ++c) {
      int x = (c*256 + tid) << 4;                 // K: row = x>>8 (256 B rows)
      float4 val = *reinterpret_cast<const float4*>(gk + x);
      *reinterpret_cast<float4*>(lk + (x ^ (((x >> 8) & 7) << 4))) = val;
    }
    #pragma unroll
    for (int c = 0; c < 8; ++c) {
      int x = (c*256 + tid) << 4;                 // V: row = x>>7 (128 B rows)
      float4 val = *reinterpret_cast<const float4*>(gv + x);
      *reinterpret_cast<float4*>(lv + (x ^ (((x >> 7) & 7) << 4))) = val;
    }
  }
  __syncthreads();
  // QK^T from LDS + in-register softmax
  float sv[4][4];
  #pragma unroll
  for (int nt = 0; nt < 4; ++nt) {
    f4 acc = {0.f,0.f,0.f,0.f};
    #pragma unroll
    for (int kt = 0; kt < 4; ++kt)
      acc = mfma16(aq[kt], ldswz(Kl, nt*16 + (l & 15), kt*64 + ((l >> 4) << 4), 256), acc);
    #pragma unroll
    for (int reg = 0; reg < 4; ++reg) sv[nt][reg] = acc[reg] * ATT_SCALE;
  }
  if ((l & 15) > 0) { sv[3][0] = -1e30f; sv[3][1] = -1e30f; sv[3][2] = -1e30f; sv[3][3] = -1e30f; }
  regSoftmax(sv);
  // wave-private P transpose through LDS (no barrier needed)
  #pragma unroll
  for (int nt = 0; nt < 4; ++nt)
    #pragma unroll
    for (int reg = 0; reg < 4; ++reg)
      bufP[(w*16 + ((l>>4)<<2) + reg)*72 + nt*16 + (l&15)] = f2b(sv[nt][reg]);
  bf8v ap0 = ldfrag(bufP, w*16, 0, 72, l);
  bf8v ap1 = ldfrag(bufP, w*16, 32, 72, l);
  float sqa = 0.f;
  #pragma unroll
  for (int nt2 = 0; nt2 < 16; ++nt2) {
    f4 acc = {0.f,0.f,0.f,0.f};
    acc = mfma16(ap0, ldswz(Vl, nt2*16 + (l & 15), ((l >> 4) << 4), 128), acc);
    acc = mfma16(ap1, ldswz(Vl, nt2*16 + (l & 15), 64 + ((l >> 4) << 4), 128), acc);
    int c = nt2*16 + (l & 15);
    float bias = epb[c];
    float hw = 0.f;
    #pragma unroll
    for (int reg = 0; reg < 4; ++reg) {
      int p = w*16 + ((l>>4)<<2) + reg;
      if (p < 49) { float v = acc[reg] + bias; hw += v; sqa += v*v; }
    }
    hw += __shfl_xor(hw, 16);
    hw += __shfl_xor(hw, 32);
    if ((l >> 4) == 0) redH[w*256 + c] = hw;
  }
  __syncthreads();
  float hwtot = redH[tid] + redH[256+tid] + redH[512+tid] + redH[768+tid];
  hws[(((size_t)(b*25+e)*16) + t)*256 + tid] = hwtot;
  reduce2Atomic(hwtot, sqa, gs1 + e, gs2 + e, redS);
}

// f_e = gem-BN applied to hw-mean
__global__ void __launch_bounds__(256) s2finker(const float* hws, const float* gs1, const float* gs2,
                                                const float* gg, const float* gb, float* EDG) {
  int blk = blockIdx.x;
  int e = (blk >> 4) % 25;
  size_t idx = (size_t)blk*256 + threadIdx.x;
  constexpr float invCnt = 1.f/1605632.f;
  float m = gs1[e]*invCnt;
  float var = gs2[e]*invCnt - m*m;
  float rstd = rsqrtf(var + 1e-5f);
  EDG[idx] = gg[e]*((hws[idx]*(1.f/49.f) - m)*rstd) + gb[e];
}

// ---------- GNN kernels (f32, unchanged) ----------

__global__ void __launch_bounds__(256) gnnProj(const float* X, const float* EDG,
    const float* Wa, const float* Wb, const float* Wu, const float* Wv, const float* We,
    float* xA, float* xB, float* xU, float* xV, float* eE) {
  int blk = blockIdx.x, tid = threadIdx.x;
  const float* src; const float* W; float* dst; int r0;
  if (blk < 160) {
    int m = blk / 40; r0 = (blk % 40) * 16;
    src = X;
    W   = (m==0)?Wa:(m==1)?Wb:(m==2)?Wu:Wv;
    dst = (m==0)?xA:(m==1)?xB:(m==2)?xU:xV;
  } else { r0 = (blk-160)*16; src = EDG; W = We; dst = eE; }
  float acc[16];
  #pragma unroll
  for (int r = 0; r < 16; ++r) acc[r] = 0.f;
  for (int c = 0; c < 256; c += 4) {
    float w0 = W[(size_t)(c+0)*256 + tid];
    float w1 = W[(size_t)(c+1)*256 + tid];
    float w2 = W[(size_t)(c+2)*256 + tid];
    float w3 = W[(size_t)(c+3)*256 + tid];
    #pragma unroll
    for (int r = 0; r < 16; ++r) {
      float4 a = *reinterpret_cast<const float4*>(&src[(size_t)(r0+r)*256 + c]);
      acc[r] += a.x*w0 + a.y*w1 + a.z*w2 + a.w*w3;
    }
  }
  #pragma unroll
  for (int r = 0; r < 16; ++r) dst[(size_t)(r0+r)*256 + tid] = acc[r];
}

__global__ void __launch_bounds__(256) g2a(const float* xA, const float* xB, const float* eE,
                                           float* ET, float* s1, float* s2) {
  __shared__ float red[8];
  int blk = blockIdx.x, tid = threadIdx.x;
  int b = blk / 400, e = (blk >> 4) % 25, t = blk & 15;
  int i = e / 5, j = e % 5;
  size_t ni = ((size_t)(b*5+i)*16 + t)*256 + tid;
  size_t nj = ((size_t)(b*5+j)*16 + t)*256 + tid;
  size_t ee = (size_t)blk*256 + tid;
  float v = xA[ni] + xB[nj] + eE[ee];
  ET[ee] = v;
  reduce2Atomic(v, v*v, s1 + e, s2 + e, red);
}

__global__ void __launch_bounds__(256) g2b(const float* ET, float* EDG, const float* g, const float* bb,
                                           const float* s1, const float* s2) {
  int blk = blockIdx.x, tid = threadIdx.x;
  int e = (blk >> 4) % 25;
  size_t ee = (size_t)blk*256 + tid;
  constexpr float invCnt = 1.f/32768.f;
  float m = s1[e]*invCnt;
  float var = s2[e]*invCnt - m*m;
  float rstd = rsqrtf(var + 1e-5f);
  float v = g[e]*((ET[ee]-m)*rstd) + bb[e];
  if (v != v) v = 0.f;
  EDG[ee] += fmaxf(v, 0.f);
}

__global__ void __launch_bounds__(256) g3a(const float* EDG, const float* xV, const float* xU,
                                           float* XN, float* s1, float* s2) {
  __shared__ float red[8];
  int blk = blockIdx.x, tid = threadIdx.x;
  int b = blk / 80, i = (blk >> 4) % 5, t = blk & 15;
  float ex[5]; float ssum = 0.f;
  #pragma unroll
  for (int j = 0; j < 5; ++j) {
    float ev = EDG[((size_t)(b*25 + i*5 + j)*16 + t)*256 + tid];
    float sg = 1.f/(1.f + __expf(-ev));
    ex[j] = __expf(sg);
    ssum += ex[j];
  }
  float inv = 1.f/ssum;
  float agg = 0.f;
  #pragma unroll
  for (int j = 0; j < 5; ++j)
    agg += ex[j]*inv * xV[((size_t)(b*5+j)*16 + t)*256 + tid];
  agg *= 0.2f;
  size_t ni = (size_t)blk*256 + tid;
  float xn = xU[ni] + agg;
  XN[ni] = xn;
  reduce2Atomic(xn, xn*xn, s1 + i, s2 + i, red);
}

__global__ void __launch_bounds__(256) g3b(const float* XN, float* X, const float* g, const float* bb,
                                           const float* s1, const float* s2, int mask) {
  int blk = blockIdx.x, tid = threadIdx.x;
  int i = (blk >> 4) % 5;
  size_t ni = (size_t)blk*256 + tid;
  constexpr float invCnt = 1.f/32768.f;
  float m = s1[i]*invCnt;
  float var = s2[i]*invCnt - m*m;
  float rstd = rsqrtf(var + 1e-5f);
  float v = g[i]*((XN[ni]-m)*rstd) + bb[i];
  if (mask && v != v) v = 0.f;
  X[ni] = fmaxf(X[ni] + v, 0.f);
}

__global__ void __launch_bounds__(256) finker(const float* X, const float* EDG,
                                              const float* sc, const float* efw, const float* efb,
                                              float* out) {
  __shared__ float red[12];
  int blk = blockIdx.x, tid = threadIdx.x;
  if (blk < 640) {
    int nn = (blk >> 4) % 5;
    float x = X[(size_t)blk*256 + tid];
    float s = fmaxf(sc[nn*256 + tid], 0.f);
    float xx = x*x, ss = s*s, xs = x*s;
    #pragma unroll
    for (int off = 32; off; off >>= 1) {
      xx += __shfl_down(xx, off); ss += __shfl_down(ss, off); xs += __shfl_down(xs, off);
    }
    if ((tid & 63) == 0) { int w = tid >> 6; red[w*3] = xx; red[w*3+1] = ss; red[w*3+2] = xs; }
    __syncthreads();
    if (tid == 0) {
      float sxx = red[0]+red[3]+red[6]+red[9];
      float sss = red[1]+red[4]+red[7]+red[10];
      float sxs = red[2]+red[5]+red[8]+red[11];
      float nx = fmaxf(sqrtf(sxx), 1e-12f);
      float ns = fmaxf(sqrtf(sss), 1e-12f);
      out[blk] = sxs / (nx * ns);
    }
  } else {
    int eb = blk - 640;
    float v = EDG[(size_t)eb*256 + tid] * efw[tid];
    #pragma unroll
    for (int off = 32; off; off >>= 1) v += __shfl_down(v, off);
    if ((tid & 63) == 0) red[tid >> 6] = v;
    __syncthreads();
    if (tid == 0) out[640 + eb] = red[0]+red[1]+red[2]+red[3] + efb[0];
  }
}

// ---------- host ----------

extern "C" void kernel_launch(void* const* d_in, const int* in_sizes, int n_in,
                              void* d_out, int out_size, void* d_ws, size_t ws_size,
                              hipStream_t stream) {
  (void)in_sizes; (void)n_in; (void)out_size; (void)ws_size;
  const float* af    = (const float*)d_in[0];
  const float* ef    = (const float*)d_in[1];
  const float* gfm   = (const float*)d_in[2];
  const float* attf  = (const float*)d_in[3];
  const float* sfm   = (const float*)d_in[4];
  const float* fam_q = (const float*)d_in[5];
  const float* fam_k = (const float*)d_in[6];
  const float* fam_v = (const float*)d_in[7];
  const float* arm_q = (const float*)d_in[8];
  const float* arm_k = (const float*)d_in[9];
  const float* arm_v = (const float*)d_in[10];
  const float* epw   = (const float*)d_in[11];
  const float* epb   = (const float*)d_in[12];
  const float* gemg  = (const float*)d_in[13];
  const float* gemb  = (const float*)d_in[14];
  const float* Us[2]   = {(const float*)d_in[15], (const float*)d_in[20]};
  const float* Vs[2]   = {(const float*)d_in[16], (const float*)d_in[21]};
  const float* As[2]   = {(const float*)d_in[17], (const float*)d_in[22]};
  const float* Bs[2]   = {(const float*)d_in[18], (const float*)d_in[23]};
  const float* Es[2]   = {(const float*)d_in[19], (const float*)d_in[24]};
  const float* bnvg[2] = {(const float*)d_in[25], (const float*)d_in[29]};
  const float* bnvb[2] = {(const float*)d_in[26], (const float*)d_in[30]};
  const float* bneg[2] = {(const float*)d_in[27], (const float*)d_in[31]};
  const float* bneb[2] = {(const float*)d_in[28], (const float*)d_in[32]};
  const float* scp  = (const float*)d_in[33];
  const float* efw  = (const float*)d_in[34];
  const float* efb  = (const float*)d_in[35];

  char* ws = (char*)d_ws;
  bhalf* PT  = (bhalf*)(ws + O_PT);
  bhalf* WTS = (bhalf*)(ws + O_WTS);
  bhalf* K1B = (bhalf*)(ws + O_K1B);
  bhalf* V1B = (bhalf*)(ws + O_V1B);
  bhalf* VQT = (bhalf*)(ws + O_VQT);
  bhalf* VKT = (bhalf*)(ws + O_VKT);
  bhalf* VTB = (bhalf*)(ws + O_VTB);
  bhalf* VWT = (bhalf*)(ws + O_VWT);
  bhalf* Q2B = (bhalf*)(ws + O_Q2B);
  bhalf* K2B = (bhalf*)(ws + O_K2B);
  bhalf* W2T = (bhalf*)(ws + O_W2T);
  float* FV  = (float*)(ws + O_FV);
  float* HWS = (float*)(ws + O_HWS);
  float* EDG = (float*)(ws + O_EDG);
  float* st  = (float*)(ws + O_ST);
  float* XA  = (float*)(ws + O_XA);
  float* XB  = (float*)(ws + O_XB);
  float* XU  = (float*)(ws + O_XU);
  float* XV  = (float*)(ws + O_XV);
  float* EE  = (float*)(ws + O_EE);
  float* ET  = (float*)(ws + O_ET);
  float* XN  = (float*)(ws + O_XN);

  hipMemsetAsync(st, 0, 256*sizeof(float), stream);

  wprep<<<1280, TPB, 0, stream>>>(fam_q, fam_k, fam_v, arm_q, arm_k, arm_v, epw, WTS);
  modprep<<<640, TPB, 0, stream>>>(af, ef, gfm, attf, sfm, PT, FV);
  kv1a<<<dim3(128, 3), TPB, 0, stream>>>(PT, WTS, K1B, V1B);
  kv1b<<<dim3(128, 3), TPB, 0, stream>>>(V1B, WTS, VQT, VKT, VTB);
  kv1c<<<dim3(128, 2), TPB, 0, stream>>>(VTB, WTS, VWT);
  s1ker<<<640, TPB, 0, stream>>>(PT, WTS, K1B, VQT, VKT, VWT, Q2B, K2B, W2T);
  s2ker<<<3200, TPB, 0, stream>>>(Q2B, K2B, W2T, epb, HWS, st+0, st+25);
  s2finker<<<3200, TPB, 0, stream>>>(HWS, st+0, st+25, gemg, gemb, EDG);

  for (int L = 0; L < 2; ++L) {
    float* es1 = st + 64 + L*64;
    float* es2 = es1 + 25;
    float* ns1 = es1 + 50;
    float* ns2 = es1 + 55;
    gnnProj<<<360, TPB, 0, stream>>>(FV, EDG, As[L], Bs[L], Us[L], Vs[L], Es[L],
                                     XA, XB, XU, XV, EE);
    g2a<<<3200, TPB, 0, stream>>>(XA, XB, EE, ET, es1, es2);
    g2b<<<3200, TPB, 0, stream>>>(ET, EDG, bneg[L], bneb[L], es1, es2);
    g3a<<<640, TPB, 0, stream>>>(EDG, XV, XU, XN, ns1, ns2);
    g3b<<<640, TPB, 0, stream>>>(XN, FV, bnvg[L], bnvb[L], ns1, ns2, L == 0 ? 1 : 0);
  }

  finker<<<3840, TPB, 0, stream>>>(FV, EDG, scp, efw, efb, (float*)d_out);
}

// Round 4
// 433.680 us; speedup vs baseline: 1.2462x; 1.0293x over previous
//
#include <hip/hip_runtime.h>

#define DEV __device__ __forceinline__

typedef unsigned short bhalf;
typedef __attribute__((ext_vector_type(8))) short bf8v;
typedef __attribute__((ext_vector_type(4))) float f4;

namespace {
constexpr int TPB = 256;
constexpr float ATT_SCALE = 0.08838834764831845f; // 1/sqrt(128)

// ---- workspace byte offsets ----
constexpr size_t O_PT  = 0;          // bf16 [640][64][256]  modalities, zero-pad rows
constexpr size_t O_WTS = 20971520;   // bf16 transposed weights (see W_* below)
constexpr size_t O_K1B = 21626880;   // bf16 [128][64][128]
constexpr size_t O_V1B = 23724032;   // bf16 [128][64][256]
constexpr size_t O_VQT = 27918336;   // bf16 [128][128][64]  (v1@arm_q)^T
constexpr size_t O_VKT = 30015488;   // bf16 [128][128][64]
constexpr size_t O_VTB = 32112640;   // bf16 [128][64][256]  v1@arm_v
constexpr size_t O_VWT = 36306944;   // bf16 [128][256][64]  (vt@epw)^T
constexpr size_t O_Q2B = 40501248;   // bf16 [640][64][128]
constexpr size_t O_K2B = 50987008;   // bf16 [640][64][128]
constexpr size_t O_W2T = 61472768;   // bf16 [640][256][64]
constexpr size_t O_FV  = 82444288;   // f32  [640][256]  node features X
constexpr size_t O_HWS = 83099648;   // f32  [3200][256]
constexpr size_t O_EDG = 86376448;   // f32  [3200][256]
constexpr size_t O_ST  = 89653248;   // f32  [256] stats
constexpr size_t O_XA  = 89654272;
constexpr size_t O_XB  = 90309632;
constexpr size_t O_XU  = 90964992;
constexpr size_t O_XV  = 91620352;
constexpr size_t O_EE  = 92275712;
constexpr size_t O_ET  = 95552512;
constexpr size_t O_XN  = 98829312;

// WTS element offsets (bf16 elems), all stored as Wt[n][k=256]
constexpr size_t W_FAMQ = 0, W_FAMK = 32768, W_ARMQ = 65536, W_ARMK = 98304,
                 W_FAMV = 131072, W_ARMV = 196608, W_EPW = 262144;
} // namespace

// ---------- helpers ----------

DEV bhalf f2b(float f) {
  unsigned u = __float_as_uint(f);
  return (bhalf)((u + 0x7FFFu + ((u >> 16) & 1u)) >> 16);
}

DEV f4 mfma16(bf8v a, bf8v b, f4 c) {
  return __builtin_amdgcn_mfma_f32_16x16x32_bf16(a, b, c, 0, 0, 0);
}

// fragment load: lane l reads row (r0 + (l&15)), 8 contiguous k at k0 + (l>>4)*8
DEV bf8v ldfrag(const bhalf* base, int r0, int k0, int S, int l) {
  return *reinterpret_cast<const bf8v*>(base + (size_t)(r0 + (l & 15)) * S + k0 + ((l >> 4) << 3));
}

// swizzled LDS fragment load: byte = row*stride + koffB, XOR'd with ((row&7)<<4)
DEV bf8v ldswz(const bhalf* base, int row, int koffB, int strideB) {
  int byte = row * strideB + koffB;
  byte ^= ((row & 7) << 4);
  return *reinterpret_cast<const bf8v*>(reinterpret_cast<const char*>(base) + byte);
}

// in-register row softmax: sv[nt][reg], row per reg spans cols nt*16+(l&15) across 16 lanes
DEV void regSoftmax(float sv[4][4]) {
  #pragma unroll
  for (int reg = 0; reg < 4; ++reg) {
    float m = fmaxf(fmaxf(sv[0][reg], sv[1][reg]), fmaxf(sv[2][reg], sv[3][reg]));
    #pragma unroll
    for (int off = 1; off <= 8; off <<= 1) m = fmaxf(m, __shfl_xor(m, off));
    float s = 0.f;
    #pragma unroll
    for (int nt = 0; nt < 4; ++nt) { float e = __expf(sv[nt][reg] - m); sv[nt][reg] = e; s += e; }
    #pragma unroll
    for (int off = 1; off <= 8; off <<= 1) s += __shfl_xor(s, off);
    float inv = 1.f / s;
    #pragma unroll
    for (int nt = 0; nt < 4; ++nt) sv[nt][reg] *= inv;
  }
}

DEV void reduce2Atomic(float a, float b, float* ga, float* gb, float* red) {
  #pragma unroll
  for (int off = 32; off; off >>= 1) { a += __shfl_down(a, off); b += __shfl_down(b, off); }
  if ((threadIdx.x & 63) == 0) { int w = threadIdx.x >> 6; red[w*2] = a; red[w*2+1] = b; }
  __syncthreads();
  if (threadIdx.x == 0) {
    atomicAdd(ga, red[0]+red[2]+red[4]+red[6]);
    atomicAdd(gb, red[1]+red[3]+red[5]+red[7]);
  }
}

// ---------- prep kernels ----------

// transpose 7 weight matrices to bf16 Wt[n][256]
__global__ void __launch_bounds__(256) wprep(const float* fq, const float* fk, const float* fv,
                                             const float* aq, const float* ak, const float* av,
                                             const float* ep, bhalf* WT) {
  int blk = blockIdx.x, tid = threadIdx.x;
  const float* src; bhalf* dst; int N, n;
  if (blk < 512) {
    int m = blk >> 7; n = blk & 127; N = 128;
    src = (m==0)?fq:(m==1)?fk:(m==2)?aq:ak;
    dst = WT + (size_t)m*32768;
  } else {
    int r = blk - 512; int m = r >> 8; n = r & 255; N = 256;
    src = (m==0)?fv:(m==1)?av:ep;
    dst = WT + 131072 + (size_t)m*65536;
  }
  dst[(size_t)n*256 + tid] = f2b(src[(size_t)tid*N + n]);
}

// per (bt,u): transpose modality slice to bf16 Pt[64][256] (zero-pad rows) + fv means
__global__ void __launch_bounds__(256) modprep(const float* af, const float* ef, const float* gf,
                                               const float* attf, const float* sf,
                                               bhalf* PT, float* FV) {
  __shared__ float lb[49*260];
  int blk = blockIdx.x, tid = threadIdx.x;
  int u = blk % 5, bt = blk / 5, b = bt >> 4, t = bt & 15;
  const float* src = (u==0)?af:(u==1)?ef:(u==2)?gf:(u==3)?attf:sf;
  src += ((size_t)b*256*16 + t)*49;
  for (int o = tid; o < 49*256; o += TPB) {
    int c = o / 49, p = o % 49;
    lb[p*260 + c] = src[(size_t)c*784 + p];
  }
  __syncthreads();
  bhalf* pt = PT + (size_t)blk*16384;
  for (int p = 0; p < 64; ++p)
    pt[p*256 + tid] = (p < 49) ? f2b(lb[p*260 + tid]) : (bhalf)0;
  float s = 0.f;
  for (int p = 0; p < 49; ++p) s += lb[p*260 + tid];
  FV[(((size_t)(b*5+u)*16) + t)*256 + tid] = s * (1.f/49.f);
}

// ---------- MFMA GEMM chain (fine nt-split over blockIdx.y for latency hiding) ----------

// per (bt, part): parts 0-1: k1 = Paf@fam_k nt quarters; parts 2-5: v1 = Paf@fam_v quarters
__global__ void __launch_bounds__(256) kv1a(const bhalf* PT, const bhalf* WT,
                                            bhalf* K1B, bhalf* V1B) {
  int bt = blockIdx.x, part = blockIdx.y;
  int tid = threadIdx.x, w = tid >> 6, l = tid & 63;
  const bhalf* A = PT + (size_t)bt*5*16384; // u=0 (af)
  bf8v a8[8];
  #pragma unroll
  for (int kt = 0; kt < 8; ++kt) a8[kt] = ldfrag(A, w*16, kt*32, 256, l);
  const bhalf* Wb; bhalf* dst; int nt0, S;
  if (part < 2) { Wb = WT + W_FAMK; dst = K1B + (size_t)bt*8192;  nt0 = part*4;     S = 128; }
  else          { Wb = WT + W_FAMV; dst = V1B + (size_t)bt*16384; nt0 = (part-2)*4; S = 256; }
  #pragma unroll
  for (int nn = 0; nn < 4; ++nn) {
    int nt = nt0 + nn;
    f4 acc = {0.f,0.f,0.f,0.f};
    #pragma unroll
    for (int kt = 0; kt < 8; ++kt)
      acc = mfma16(a8[kt], ldfrag(Wb, nt*16, kt*32, 256, l), acc);
    #pragma unroll
    for (int reg = 0; reg < 4; ++reg) {
      int p = w*16 + ((l>>4)<<2) + reg;
      dst[(size_t)p*S + nt*16 + (l&15)] = f2b(acc[reg]);
    }
  }
}

// per (bt, part): parts 0-1: vqt; 2-3: vkt (transposed [128][64]); 4-7: vtb quarters
__global__ void __launch_bounds__(256) kv1b(const bhalf* V1B, const bhalf* WT,
                                            bhalf* VQT, bhalf* VKT, bhalf* VTB) {
  int bt = blockIdx.x, part = blockIdx.y;
  int tid = threadIdx.x, w = tid >> 6, l = tid & 63;
  const bhalf* A = V1B + (size_t)bt*16384;
  bf8v a8[8];
  #pragma unroll
  for (int kt = 0; kt < 8; ++kt) a8[kt] = ldfrag(A, w*16, kt*32, 256, l);
  if (part < 4) {
    const bhalf* Wb = WT + ((part < 2) ? W_ARMQ : W_ARMK);
    bhalf* o = ((part < 2) ? VQT : VKT) + (size_t)bt*8192;
    int nt0 = (part & 1) * 4;
    #pragma unroll
    for (int nn = 0; nn < 4; ++nn) {
      int nt = nt0 + nn;
      f4 acc = {0.f,0.f,0.f,0.f};
      #pragma unroll
      for (int kt = 0; kt < 8; ++kt)
        acc = mfma16(a8[kt], ldfrag(Wb, nt*16, kt*32, 256, l), acc);
      #pragma unroll
      for (int reg = 0; reg < 4; ++reg) {
        int p = w*16 + ((l>>4)<<2) + reg;
        int n = nt*16 + (l&15);
        o[(size_t)n*64 + p] = f2b(acc[reg]);   // transposed store
      }
    }
  } else {
    bhalf* ov = VTB + (size_t)bt*16384;
    int nt0 = (part - 4) * 4;
    #pragma unroll
    for (int nn = 0; nn < 4; ++nn) {
      int nt = nt0 + nn;
      f4 acc = {0.f,0.f,0.f,0.f};
      #pragma unroll
      for (int kt = 0; kt < 8; ++kt)
        acc = mfma16(a8[kt], ldfrag(WT + W_ARMV, nt*16, kt*32, 256, l), acc);
      #pragma unroll
      for (int reg = 0; reg < 4; ++reg) {
        int p = w*16 + ((l>>4)<<2) + reg;
        ov[(size_t)p*256 + nt*16 + (l&15)] = f2b(acc[reg]);
      }
    }
  }
}

// per (bt, part): vwt = (vt@epw)^T [256][64], nt quarters
__global__ void __launch_bounds__(256) kv1c(const bhalf* VTB, const bhalf* WT, bhalf* VWT) {
  int bt = blockIdx.x, part = blockIdx.y;
  int tid = threadIdx.x, w = tid >> 6, l = tid & 63;
  const bhalf* A = VTB + (size_t)bt*16384;
  bf8v a8[8];
  #pragma unroll
  for (int kt = 0; kt < 8; ++kt) a8[kt] = ldfrag(A, w*16, kt*32, 256, l);
  bhalf* ow = VWT + (size_t)bt*16384;
  int nt0 = part * 4;
  #pragma unroll
  for (int nn = 0; nn < 4; ++nn) {
    int nt = nt0 + nn;
    f4 acc = {0.f,0.f,0.f,0.f};
    #pragma unroll
    for (int kt = 0; kt < 8; ++kt)
      acc = mfma16(a8[kt], ldfrag(WT + W_EPW, nt*16, kt*32, 256, l), acc);
    #pragma unroll
    for (int reg = 0; reg < 4; ++reg) {
      int p = w*16 + ((l>>4)<<2) + reg;
      ow[(size_t)(nt*16 + (l&15))*64 + p] = f2b(acc[reg]);  // transposed
    }
  }
}

// ---------- stage 1: FAM attention + ARM input projections ----------
// per (bt,u): q1 = Pt@fam_q; P = softmax(q1 k1^T * s); q2 = P@vq, k2 = P@vk, w2t = (P@vw)^T
// VQT/VKT tiles (16 KB each) T14-staged: global loads at top, swizzled ds_writes
// after phase 1 (MFMA-covered latency); phase-3 q2/k2 operands come from LDS.
__global__ void __launch_bounds__(256) s1ker(const bhalf* PT, const bhalf* WT,
    const bhalf* K1B, const bhalf* VQT, const bhalf* VKT, const bhalf* VWT,
    bhalf* Q2B, bhalf* K2B, bhalf* W2T)
{
  __shared__ bhalf bufA[64*280];  // q1 staging, then w2 staging
  __shared__ bhalf bufP[64*72];
  __shared__ bhalf vqL[64*128];   // 16 KB, swizzled rows of 128 B
  __shared__ bhalf vkL[64*128];   // 16 KB
  int blk = blockIdx.x;           // bt*5 + u
  int bt = blk / 5;
  int tid = threadIdx.x, w = tid >> 6, l = tid & 63;
  const bhalf* Pt = PT + (size_t)blk*16384;
  // T14 issue-early: vq/vk tile loads (consumed after phase 1)
  float4 stg[8];
  {
    const char* gq = reinterpret_cast<const char*>(VQT + (size_t)bt*8192);
    const char* gk = reinterpret_cast<const char*>(VKT + (size_t)bt*8192);
    #pragma unroll
    for (int c = 0; c < 4; ++c) stg[c]   = *reinterpret_cast<const float4*>(gq + ((c*256 + tid) << 4));
    #pragma unroll
    for (int c = 0; c < 4; ++c) stg[4+c] = *reinterpret_cast<const float4*>(gk + ((c*256 + tid) << 4));
  }
  // phase 1: q1 (M=64, N=128, K=256) -> bufA bf16
  {
    bf8v a8[8];
    #pragma unroll
    for (int kt = 0; kt < 8; ++kt) a8[kt] = ldfrag(Pt, w*16, kt*32, 256, l);
    #pragma unroll
    for (int nt = 0; nt < 8; ++nt) {
      f4 acc = {0.f,0.f,0.f,0.f};
      #pragma unroll
      for (int kt = 0; kt < 8; ++kt)
        acc = mfma16(a8[kt], ldfrag(WT + W_FAMQ, nt*16, kt*32, 256, l), acc);
      #pragma unroll
      for (int reg = 0; reg < 4; ++reg)
        bufA[(w*16 + ((l>>4)<<2) + reg)*280 + nt*16 + (l&15)] = f2b(acc[reg]);
    }
  }
  // T14 write-late: swizzled LDS writes of vq/vk
  {
    char* lq = reinterpret_cast<char*>(vqL);
    char* lk = reinterpret_cast<char*>(vkL);
    #pragma unroll
    for (int c = 0; c < 4; ++c) {
      int x = (c*256 + tid) << 4;               // row = x>>7 (128 B rows)
      int xs = x ^ (((x >> 7) & 7) << 4);
      *reinterpret_cast<float4*>(lq + xs) = stg[c];
      *reinterpret_cast<float4*>(lk + xs) = stg[4+c];
    }
  }
  __syncthreads();
  // phase 2: scores vs k1 (own-wave rows from bufA), softmax in regs
  float sv[4][4];
  {
    const bhalf* K1 = K1B + (size_t)bt*8192;
    bf8v aq[4];
    #pragma unroll
    for (int kt = 0; kt < 4; ++kt) aq[kt] = ldfrag(bufA, w*16, kt*32, 280, l);
    #pragma unroll
    for (int nt = 0; nt < 4; ++nt) {
      f4 acc = {0.f,0.f,0.f,0.f};
      #pragma unroll
      for (int kt = 0; kt < 4; ++kt)
        acc = mfma16(aq[kt], ldfrag(K1, nt*16, kt*32, 128, l), acc);
      #pragma unroll
      for (int reg = 0; reg < 4; ++reg) sv[nt][reg] = acc[reg] * ATT_SCALE;
    }
  }
  if ((l & 15) > 0) { sv[3][0] = -1e30f; sv[3][1] = -1e30f; sv[3][2] = -1e30f; sv[3][3] = -1e30f; }
  regSoftmax(sv);
  #pragma unroll
  for (int nt = 0; nt < 4; ++nt)
    #pragma unroll
    for (int reg = 0; reg < 4; ++reg)
      bufP[(w*16 + ((l>>4)<<2) + reg)*72 + nt*16 + (l&15)] = f2b(sv[nt][reg]);
  __syncthreads();
  // phase 3: PVs
  bf8v ap0 = ldfrag(bufP, w*16, 0, 72, l);
  bf8v ap1 = ldfrag(bufP, w*16, 32, 72, l);
  {
    bhalf* q2 = Q2B + (size_t)blk*8192;
    #pragma unroll
    for (int nt = 0; nt < 8; ++nt) {
      f4 acc = {0.f,0.f,0.f,0.f};
      acc = mfma16(ap0, ldswz(vqL, nt*16 + (l & 15), ((l >> 4) << 4), 128), acc);
      acc = mfma16(ap1, ldswz(vqL, nt*16 + (l & 15), 64 + ((l >> 4) << 4), 128), acc);
      #pragma unroll
      for (int reg = 0; reg < 4; ++reg) {
        int p = w*16 + ((l>>4)<<2) + reg;
        q2[(size_t)p*128 + nt*16 + (l&15)] = (p < 49) ? f2b(acc[reg]) : (bhalf)0;
      }
    }
  }
  {
    bhalf* k2 = K2B + (size_t)blk*8192;
    #pragma unroll
    for (int nt = 0; nt < 8; ++nt) {
      f4 acc = {0.f,0.f,0.f,0.f};
      acc = mfma16(ap0, ldswz(vkL, nt*16 + (l & 15), ((l >> 4) << 4), 128), acc);
      acc = mfma16(ap1, ldswz(vkL, nt*16 + (l & 15), 64 + ((l >> 4) << 4), 128), acc);
      #pragma unroll
      for (int reg = 0; reg < 4; ++reg) {
        int p = w*16 + ((l>>4)<<2) + reg;
        k2[(size_t)p*128 + nt*16 + (l&15)] = (p < 49) ? f2b(acc[reg]) : (bhalf)0;
      }
    }
  }
  {
    const bhalf* vw = VWT + (size_t)bt*16384;
    #pragma unroll
    for (int nt = 0; nt < 16; ++nt) {
      f4 acc = {0.f,0.f,0.f,0.f};
      acc = mfma16(ap0, ldfrag(vw, nt*16, 0, 64, l), acc);
      acc = mfma16(ap1, ldfrag(vw, nt*16, 32, 64, l), acc);
      #pragma unroll
      for (int reg = 0; reg < 4; ++reg)
        bufA[(w*16 + ((l>>4)<<2) + reg)*280 + nt*16 + (l&15)] = f2b(acc[reg]);
    }
  }
  __syncthreads();
  // epilogue: w2t[c][r] coalesced (pairs packed into u32)
  unsigned* wt = reinterpret_cast<unsigned*>(W2T + (size_t)blk*16384);
  for (int it = 0; it < 32; ++it) {
    int o = it*256 + tid;       // 0..8191
    int c = o >> 5, ii = o & 31;
    int r0 = ii*2;
    unsigned lo = (r0   < 49) ? (unsigned)bufA[r0*280 + c]     : 0u;
    unsigned hi = (r0+1 < 49) ? (unsigned)bufA[(r0+1)*280 + c] : 0u;
    wt[o] = lo | (hi << 16);
  }
}

// ---------- stage 2: ARM attention + edge stats ----------
// One block per (bt,e). K and Q fragments prefetched DIRECTLY to registers
// (no LDS round-trip -> 46 KB LDS -> 3 blocks/CU); V staged to XOR-swizzled LDS
// (each wave reads all of V, 4x reuse). V-staging loads issue first so the
// ds_write waitcnts don't drain the K/Q prefetches. 2 block-wide barriers.
// XCD-bijective remap groups the 25 e-blocks of one bt on one XCD (L2 reuse).
__global__ void __launch_bounds__(256) s2ker(const bhalf* Q2B, const bhalf* K2B, const bhalf* W2T,
    const float* epb, float* hws, float* gs1, float* gs2)
{
  __shared__ bhalf Vl[256*64];    // 32 KB, swizzled rows of 128 B
  __shared__ bhalf bufP[64*72];   // 9 KB, wave-private
  __shared__ float redH[4*256];   // 4 KB
  __shared__ float redS[8];
  int orig = blockIdx.x;
  int blk = (orig & 7) * 400 + (orig >> 3);   // 3200 = 8*400, bijective XCD grouping
  int e = blk % 25, bt = blk / 25, b = bt >> 4, t = bt & 15;
  int i = e / 5, j = e % 5;
  int tid = threadIdx.x, w = tid >> 6, l = tid & 63;
  const bhalf* K = K2B + (size_t)(bt*5 + i)*8192;
  const bhalf* V = W2T + (size_t)(bt*5 + i)*16384;
  const bhalf* Q = Q2B + (size_t)(bt*5 + j)*8192;
  // V staging loads FIRST (oldest in vmcnt order)
  float4 sv4[8];
  {
    const char* gv = reinterpret_cast<const char*>(V);
    #pragma unroll
    for (int c = 0; c < 8; ++c)
      sv4[c] = *reinterpret_cast<const float4*>(gv + ((c*256 + tid) << 4));
  }
  // Q + K fragments direct to registers (newer; survive the ds_write waits)
  bf8v aq[4];
  #pragma unroll
  for (int kt = 0; kt < 4; ++kt) aq[kt] = ldfrag(Q, w*16, kt*32, 128, l);
  bf8v kf[4][4];
  #pragma unroll
  for (int nt = 0; nt < 4; ++nt)
    #pragma unroll
    for (int kt = 0; kt < 4; ++kt) kf[nt][kt] = ldfrag(K, nt*16, kt*32, 128, l);
  // swizzled V writes
  {
    char* lv = reinterpret_cast<char*>(Vl);
    #pragma unroll
    for (int c = 0; c < 8; ++c) {
      int x = (c*256 + tid) << 4;                 // V: row = x>>7 (128 B rows)
      *reinterpret_cast<float4*>(lv + (x ^ (((x >> 7) & 7) << 4))) = sv4[c];
    }
  }
  __syncthreads();
  // QK^T: pure register MFMA chain
  float sv[4][4];
  #pragma unroll
  for (int nt = 0; nt < 4; ++nt) {
    f4 acc = {0.f,0.f,0.f,0.f};
    #pragma unroll
    for (int kt = 0; kt < 4; ++kt)
      acc = mfma16(aq[kt], kf[nt][kt], acc);
    #pragma unroll
    for (int reg = 0; reg < 4; ++reg) sv[nt][reg] = acc[reg] * ATT_SCALE;
  }
  if ((l & 15) > 0) { sv[3][0] = -1e30f; sv[3][1] = -1e30f; sv[3][2] = -1e30f; sv[3][3] = -1e30f; }
  regSoftmax(sv);
  // wave-private P transpose through LDS (no barrier needed)
  #pragma unroll
  for (int nt = 0; nt < 4; ++nt)
    #pragma unroll
    for (int reg = 0; reg < 4; ++reg)
      bufP[(w*16 + ((l>>4)<<2) + reg)*72 + nt*16 + (l&15)] = f2b(sv[nt][reg]);
  bf8v ap0 = ldfrag(bufP, w*16, 0, 72, l);
  bf8v ap1 = ldfrag(bufP, w*16, 32, 72, l);
  float sqa = 0.f;
  #pragma unroll
  for (int nt2 = 0; nt2 < 16; ++nt2) {
    f4 acc = {0.f,0.f,0.f,0.f};
    acc = mfma16(ap0, ldswz(Vl, nt2*16 + (l & 15), ((l >> 4) << 4), 128), acc);
    acc = mfma16(ap1, ldswz(Vl, nt2*16 + (l & 15), 64 + ((l >> 4) << 4), 128), acc);
    int c = nt2*16 + (l & 15);
    float bias = epb[c];
    float hw = 0.f;
    #pragma unroll
    for (int reg = 0; reg < 4; ++reg) {
      int p = w*16 + ((l>>4)<<2) + reg;
      if (p < 49) { float v = acc[reg] + bias; hw += v; sqa += v*v; }
    }
    hw += __shfl_xor(hw, 16);
    hw += __shfl_xor(hw, 32);
    if ((l >> 4) == 0) redH[w*256 + c] = hw;
  }
  __syncthreads();
  float hwtot = redH[tid] + redH[256+tid] + redH[512+tid] + redH[768+tid];
  hws[(((size_t)(b*25+e)*16) + t)*256 + tid] = hwtot;
  reduce2Atomic(hwtot, sqa, gs1 + e, gs2 + e, redS);
}

// f_e = gem-BN applied to hw-mean
__global__ void __launch_bounds__(256) s2finker(const float* hws, const float* gs1, const float* gs2,
                                                const float* gg, const float* gb, float* EDG) {
  int blk = blockIdx.x;
  int e = (blk >> 4) % 25;
  size_t idx = (size_t)blk*256 + threadIdx.x;
  constexpr float invCnt = 1.f/1605632.f;
  float m = gs1[e]*invCnt;
  float var = gs2[e]*invCnt - m*m;
  float rstd = rsqrtf(var + 1e-5f);
  EDG[idx] = gg[e]*((hws[idx]*(1.f/49.f) - m)*rstd) + gb[e];
}

// ---------- GNN kernels (f32, unchanged) ----------

__global__ void __launch_bounds__(256) gnnProj(const float* X, const float* EDG,
    const float* Wa, const float* Wb, const float* Wu, const float* Wv, const float* We,
    float* xA, float* xB, float* xU, float* xV, float* eE) {
  int blk = blockIdx.x, tid = threadIdx.x;
  const float* src; const float* W; float* dst; int r0;
  if (blk < 160) {
    int m = blk / 40; r0 = (blk % 40) * 16;
    src = X;
    W   = (m==0)?Wa:(m==1)?Wb:(m==2)?Wu:Wv;
    dst = (m==0)?xA:(m==1)?xB:(m==2)?xU:xV;
  } else { r0 = (blk-160)*16; src = EDG; W = We; dst = eE; }
  float acc[16];
  #pragma unroll
  for (int r = 0; r < 16; ++r) acc[r] = 0.f;
  for (int c = 0; c < 256; c += 4) {
    float w0 = W[(size_t)(c+0)*256 + tid];
    float w1 = W[(size_t)(c+1)*256 + tid];
    float w2 = W[(size_t)(c+2)*256 + tid];
    float w3 = W[(size_t)(c+3)*256 + tid];
    #pragma unroll
    for (int r = 0; r < 16; ++r) {
      float4 a = *reinterpret_cast<const float4*>(&src[(size_t)(r0+r)*256 + c]);
      acc[r] += a.x*w0 + a.y*w1 + a.z*w2 + a.w*w3;
    }
  }
  #pragma unroll
  for (int r = 0; r < 16; ++r) dst[(size_t)(r0+r)*256 + tid] = acc[r];
}

__global__ void __launch_bounds__(256) g2a(const float* xA, const float* xB, const float* eE,
                                           float* ET, float* s1, float* s2) {
  __shared__ float red[8];
  int blk = blockIdx.x, tid = threadIdx.x;
  int b = blk / 400, e = (blk >> 4) % 25, t = blk & 15;
  int i = e / 5, j = e % 5;
  size_t ni = ((size_t)(b*5+i)*16 + t)*256 + tid;
  size_t nj = ((size_t)(b*5+j)*16 + t)*256 + tid;
  size_t ee = (size_t)blk*256 + tid;
  float v = xA[ni] + xB[nj] + eE[ee];
  ET[ee] = v;
  reduce2Atomic(v, v*v, s1 + e, s2 + e, red);
}

__global__ void __launch_bounds__(256) g2b(const float* ET, float* EDG, const float* g, const float* bb,
                                           const float* s1, const float* s2) {
  int blk = blockIdx.x, tid = threadIdx.x;
  int e = (blk >> 4) % 25;
  size_t ee = (size_t)blk*256 + tid;
  constexpr float invCnt = 1.f/32768.f;
  float m = s1[e]*invCnt;
  float var = s2[e]*invCnt - m*m;
  float rstd = rsqrtf(var + 1e-5f);
  float v = g[e]*((ET[ee]-m)*rstd) + bb[e];
  if (v != v) v = 0.f;
  EDG[ee] += fmaxf(v, 0.f);
}

__global__ void __launch_bounds__(256) g3a(const float* EDG, const float* xV, const float* xU,
                                           float* XN, float* s1, float* s2) {
  __shared__ float red[8];
  int blk = blockIdx.x, tid = threadIdx.x;
  int b = blk / 80, i = (blk >> 4) % 5, t = blk & 15;
  float ex[5]; float ssum = 0.f;
  #pragma unroll
  for (int j = 0; j < 5; ++j) {
    float ev = EDG[((size_t)(b*25 + i*5 + j)*16 + t)*256 + tid];
    float sg = 1.f/(1.f + __expf(-ev));
    ex[j] = __expf(sg);
    ssum += ex[j];
  }
  float inv = 1.f/ssum;
  float agg = 0.f;
  #pragma unroll
  for (int j = 0; j < 5; ++j)
    agg += ex[j]*inv * xV[((size_t)(b*5+j)*16 + t)*256 + tid];
  agg *= 0.2f;
  size_t ni = (size_t)blk*256 + tid;
  float xn = xU[ni] + agg;
  XN[ni] = xn;
  reduce2Atomic(xn, xn*xn, s1 + i, s2 + i, red);
}

__global__ void __launch_bounds__(256) g3b(const float* XN, float* X, const float* g, const float* bb,
                                           const float* s1, const float* s2, int mask) {
  int blk = blockIdx.x, tid = threadIdx.x;
  int i = (blk >> 4) % 5;
  size_t ni = (size_t)blk*256 + tid;
  constexpr float invCnt = 1.f/32768.f;
  float m = s1[i]*invCnt;
  float var = s2[i]*invCnt - m*m;
  float rstd = rsqrtf(var + 1e-5f);
  float v = g[i]*((XN[ni]-m)*rstd) + bb[i];
  if (mask && v != v) v = 0.f;
  X[ni] = fmaxf(X[ni] + v, 0.f);
}

__global__ void __launch_bounds__(256) finker(const float* X, const float* EDG,
                                              const float* sc, const float* efw, const float* efb,
                                              float* out) {
  __shared__ float red[12];
  int blk = blockIdx.x, tid = threadIdx.x;
  if (blk < 640) {
    int nn = (blk >> 4) % 5;
    float x = X[(size_t)blk*256 + tid];
    float s = fmaxf(sc[nn*256 + tid], 0.f);
    float xx = x*x, ss = s*s, xs = x*s;
    #pragma unroll
    for (int off = 32; off; off >>= 1) {
      xx += __shfl_down(xx, off); ss += __shfl_down(ss, off); xs += __shfl_down(xs, off);
    }
    if ((tid & 63) == 0) { int w = tid >> 6; red[w*3] = xx; red[w*3+1] = ss; red[w*3+2] = xs; }
    __syncthreads();
    if (tid == 0) {
      float sxx = red[0]+red[3]+red[6]+red[9];
      float sss = red[1]+red[4]+red[7]+red[10];
      float sxs = red[2]+red[5]+red[8]+red[11];
      float nx = fmaxf(sqrtf(sxx), 1e-12f);
      float ns = fmaxf(sqrtf(sss), 1e-12f);
      out[blk] = sxs / (nx * ns);
    }
  } else {
    int eb = blk - 640;
    float v = EDG[(size_t)eb*256 + tid] * efw[tid];
    #pragma unroll
    for (int off = 32; off; off >>= 1) v += __shfl_down(v, off);
    if ((tid & 63) == 0) red[tid >> 6] = v;
    __syncthreads();
    if (tid == 0) out[640 + eb] = red[0]+red[1]+red[2]+red[3] + efb[0];
  }
}

// ---------- host ----------

extern "C" void kernel_launch(void* const* d_in, const int* in_sizes, int n_in,
                              void* d_out, int out_size, void* d_ws, size_t ws_size,
                              hipStream_t stream) {
  (void)in_sizes; (void)n_in; (void)out_size; (void)ws_size;
  const float* af    = (const float*)d_in[0];
  const float* ef    = (const float*)d_in[1];
  const float* gfm   = (const float*)d_in[2];
  const float* attf  = (const float*)d_in[3];
  const float* sfm   = (const float*)d_in[4];
  const float* fam_q = (const float*)d_in[5];
  const float* fam_k = (const float*)d_in[6];
  const float* fam_v = (const float*)d_in[7];
  const float* arm_q = (const float*)d_in[8];
  const float* arm_k = (const float*)d_in[9];
  const float* arm_v = (const float*)d_in[10];
  const float* epw   = (const float*)d_in[11];
  const float* epb   = (const float*)d_in[12];
  const float* gemg  = (const float*)d_in[13];
  const float* gemb  = (const float*)d_in[14];
  const float* Us[2]   = {(const float*)d_in[15], (const float*)d_in[20]};
  const float* Vs[2]   = {(const float*)d_in[16], (const float*)d_in[21]};
  const float* As[2]   = {(const float*)d_in[17], (const float*)d_in[22]};
  const float* Bs[2]   = {(const float*)d_in[18], (const float*)d_in[23]};
  const float* Es[2]   = {(const float*)d_in[19], (const float*)d_in[24]};
  const float* bnvg[2] = {(const float*)d_in[25], (const float*)d_in[29]};
  const float* bnvb[2] = {(const float*)d_in[26], (const float*)d_in[30]};
  const float* bneg[2] = {(const float*)d_in[27], (const float*)d_in[31]};
  const float* bneb[2] = {(const float*)d_in[28], (const float*)d_in[32]};
  const float* scp  = (const float*)d_in[33];
  const float* efw  = (const float*)d_in[34];
  const float* efb  = (const float*)d_in[35];

  char* ws = (char*)d_ws;
  bhalf* PT  = (bhalf*)(ws + O_PT);
  bhalf* WTS = (bhalf*)(ws + O_WTS);
  bhalf* K1B = (bhalf*)(ws + O_K1B);
  bhalf* V1B = (bhalf*)(ws + O_V1B);
  bhalf* VQT = (bhalf*)(ws + O_VQT);
  bhalf* VKT = (bhalf*)(ws + O_VKT);
  bhalf* VTB = (bhalf*)(ws + O_VTB);
  bhalf* VWT = (bhalf*)(ws + O_VWT);
  bhalf* Q2B = (bhalf*)(ws + O_Q2B);
  bhalf* K2B = (bhalf*)(ws + O_K2B);
  bhalf* W2T = (bhalf*)(ws + O_W2T);
  float* FV  = (float*)(ws + O_FV);
  float* HWS = (float*)(ws + O_HWS);
  float* EDG = (float*)(ws + O_EDG);
  float* st  = (float*)(ws + O_ST);
  float* XA  = (float*)(ws + O_XA);
  float* XB  = (float*)(ws + O_XB);
  float* XU  = (float*)(ws + O_XU);
  float* XV  = (float*)(ws + O_XV);
  float* EE  = (float*)(ws + O_EE);
  float* ET  = (float*)(ws + O_ET);
  float* XN  = (float*)(ws + O_XN);

  hipMemsetAsync(st, 0, 256*sizeof(float), stream);

  wprep<<<1280, TPB, 0, stream>>>(fam_q, fam_k, fam_v, arm_q, arm_k, arm_v, epw, WTS);
  modprep<<<640, TPB, 0, stream>>>(af, ef, gfm, attf, sfm, PT, FV);
  kv1a<<<dim3(128, 6), TPB, 0, stream>>>(PT, WTS, K1B, V1B);
  kv1b<<<dim3(128, 8), TPB, 0, stream>>>(V1B, WTS, VQT, VKT, VTB);
  kv1c<<<dim3(128, 4), TPB, 0, stream>>>(VTB, WTS, VWT);
  s1ker<<<640, TPB, 0, stream>>>(PT, WTS, K1B, VQT, VKT, VWT, Q2B, K2B, W2T);
  s2ker<<<3200, TPB, 0, stream>>>(Q2B, K2B, W2T, epb, HWS, st+0, st+25);
  s2finker<<<3200, TPB, 0, stream>>>(HWS, st+0, st+25, gemg, gemb, EDG);

  for (int L = 0; L < 2; ++L) {
    float* es1 = st + 64 + L*64;
    float* es2 = es1 + 25;
    float* ns1 = es1 + 50;
    float* ns2 = es1 + 55;
    gnnProj<<<360, TPB, 0, stream>>>(FV, EDG, As[L], Bs[L], Us[L], Vs[L], Es[L],
                                     XA, XB, XU, XV, EE);
    g2a<<<3200, TPB, 0, stream>>>(XA, XB, EE, ET, es1, es2);
    g2b<<<3200, TPB, 0, stream>>>(ET, EDG, bneg[L], bneb[L], es1, es2);
    g3a<<<640, TPB, 0, stream>>>(EDG, XV, XU, XN, ns1, ns2);
    g3b<<<640, TPB, 0, stream>>>(XN, FV, bnvg[L], bnvb[L], ns1, ns2, L == 0 ? 1 : 0);
  }

  finker<<<3840, TPB, 0, stream>>>(FV, EDG, scp, efw, efb, (float*)d_out);
}